// Round 1
// baseline (299.207 us; speedup 1.0000x reference)
//
#include <hip/hip_runtime.h>
#include <math.h>

#define TPB 256
#define STRIDE 129            // 128 + 1 pad: conflict-free rows AND columns
#define NPIX 4096             // 64*64
#define NJ 17
#define NL 16
#define NBV 16                // bs*nv
#define NIMG 256              // NBV*NL
#define NJP 272               // NBV*NJ
static constexpr float kBeta = 100.0f;

// output layout (floats): kps(544) | comb_v(768) | comb_p(512) | fields_new(3145728) | hms_new(1114112)
#define O_KPS 0
#define O_CV 544
#define O_CP 1312
#define O_FN 1824
#define O_HM 3147552
// workspace layout (floats)
#define W_HMC 0               // centered heatmaps, 272*4096
#define W_STDHM 1114112       // 272
#define W_SF 1114384          // 256 (std_df/(std_df+1e-6))
#define W_FDS 1114640         // 256*4096 scaled fds2jts
#define W_W1 2163216          // FFT(kernel1), 128*128 complex
#define W_W2 2195984

__device__ __constant__ int c_P0[16] = {0,1,2,0,4,5,0,7,8,9,8,11,12,8,14,15};
__device__ __constant__ int c_P1[16] = {1,2,3,4,5,6,7,8,9,10,11,12,13,14,15,16};
// per-joint limb index for prox multiplier (-1 = none), and dist multiplier (j-1 or -1)
__device__ __constant__ int c_proxL[17] = {6,1,2,-1,4,5,-1,7,13,9,-1,11,12,-1,14,15,-1};
__device__ __constant__ int c_distL[17] = {-1,0,1,2,3,4,5,6,7,8,9,10,11,12,13,14,15};

// ---------------- FFT core (radix-2, DIF fwd natural->bitrev, DIT inv bitrev->natural) ----
// Lines of 128 complex points in LDS. ROWS: addr = line*STRIDE + pos ; else pos*STRIDE + line.
template<bool INV, bool ROWS>
__device__ void fft_pass(float* __restrict__ re, float* __restrict__ im,
                         const float* __restrict__ twr, const float* __restrict__ twi,
                         int nlines, int tid) {
  const int nbf = nlines << 6;   // nlines * 64 butterflies per stage
  if (!INV) {
    int step = 1;
    for (int m = 128; m >= 2; m >>= 1) {
      const int half = m >> 1;
      const int jm = half - 1;
      for (int idx = tid; idx < nbf; idx += TPB) {
        const int line = idx >> 6;
        const int b = idx & 63;
        const int j = b & jm;
        const int p0 = ((b & ~jm) << 1) | j;
        const int p1 = p0 + half;
        const int a0 = ROWS ? line * STRIDE + p0 : p0 * STRIDE + line;
        const int a1 = ROWS ? line * STRIDE + p1 : p1 * STRIDE + line;
        const float ur = re[a0], ui = im[a0];
        const float vr = re[a1], vi = im[a1];
        re[a0] = ur + vr; im[a0] = ui + vi;
        const float dr = ur - vr, di = ui - vi;
        const int k = j * step;
        const float wr = twr[k], wi = twi[k];       // e^{-2pi i k/128}
        re[a1] = dr * wr - di * wi;
        im[a1] = dr * wi + di * wr;
      }
      step <<= 1;
      __syncthreads();
    }
  } else {
    int step = 64;
    for (int m = 2; m <= 128; m <<= 1) {
      const int half = m >> 1;
      const int jm = half - 1;
      for (int idx = tid; idx < nbf; idx += TPB) {
        const int line = idx >> 6;
        const int b = idx & 63;
        const int j = b & jm;
        const int p0 = ((b & ~jm) << 1) | j;
        const int p1 = p0 + half;
        const int a0 = ROWS ? line * STRIDE + p0 : p0 * STRIDE + line;
        const int a1 = ROWS ? line * STRIDE + p1 : p1 * STRIDE + line;
        const float ur = re[a0], ui = im[a0];
        const float vr = re[a1], vi = im[a1];
        const int k = j * step;
        const float wr = twr[k], wi = twi[k];
        const float tr = vr * wr + vi * wi;         // v * conj(w)
        const float ti = vi * wr - vr * wi;
        re[a0] = ur + tr; im[a0] = ui + ti;
        re[a1] = ur - tr; im[a1] = ui - ti;
      }
      step >>= 1;
      __syncthreads();
    }
  }
}

__device__ inline void fft_init(float* re, float* im, float* twr, float* twi, int tid) {
  for (int i = tid; i < 128 * STRIDE; i += TPB) { re[i] = 0.0f; im[i] = 0.0f; }
  if (tid < 64) {
    float s, c;
    sincosf(-3.14159265358979323846f * (float)tid / 64.0f, &s, &c);
    twr[tid] = c; twi[tid] = s;
  }
  __syncthreads();
}

__device__ inline void fft_mult(float* re, float* im, const float* Wk, int tid) {
  const float2* W2p = (const float2*)Wk;
  for (int i = tid; i < 16384; i += TPB) {
    const int r = i >> 7, c = i & 127;
    const int a = r * STRIDE + c;
    const float2 w = W2p[i];
    const float ar = re[a], ai = im[a];
    re[a] = ar * w.x - ai * w.y;
    im[a] = ar * w.y + ai * w.x;
  }
  __syncthreads();
}

// ---------------- prep: build wrapped complex kernels, FFT, store (1/16384 folded) --------
__global__ __launch_bounds__(TPB) void prep_kernel(float* __restrict__ W1, float* __restrict__ W2) {
  __shared__ float re[128 * STRIDE];
  __shared__ float im[128 * STRIDE];
  __shared__ float twr[64], twi[64];
  const int tid = threadIdx.x;
  const int blk = blockIdx.x;
  fft_init(re, im, twr, twi, tid);
  for (int i = tid; i < 16384; i += TPB) {
    const int r = i >> 7, c = i & 127;
    const int dy = (r < 64) ? r : r - 128;
    const int dx = (c < 64) ? c : c - 128;
    float a, b;
    if (blk == 0) { a = 1.0f - (float)dy; b = 1.0f - (float)dx; }   // w1 = 1/((1-dy)+i(1-dx))
    else          { a = 1.0f + (float)dy; b = 1.0f + (float)dx; }   // w2 = 1/((1+dy)+i(1+dx))
    const float den = a * a + b * b;
    float vr = 0.0f, vi = 0.0f;
    if (r != 64 && c != 64 && den > 0.0f) {
      const float inv = 1.0f / den;
      vr = a * inv; vi = -b * inv;
    }
    re[r * STRIDE + c] = vr;
    im[r * STRIDE + c] = vi;
  }
  __syncthreads();
  fft_pass<false, true>(re, im, twr, twi, 128, tid);
  fft_pass<false, false>(re, im, twr, twi, 128, tid);
  float* Wo = (blk == 0) ? W1 : W2;
  const float scl = 1.0f / 16384.0f;
  for (int i = tid; i < 16384; i += TPB) {
    const int r = i >> 7, c = i & 127;
    const int a = r * STRIDE + c;
    Wo[2 * i] = re[a] * scl;
    Wo[2 * i + 1] = im[a] * scl;
  }
}

// ---------------- heatmap stats: center + std (ddof=1) ------------------------------------
__global__ __launch_bounds__(TPB) void hm_stats_kernel(const float* __restrict__ hm,
                                                       float* __restrict__ hm_c,
                                                       float* __restrict__ std_hm) {
  __shared__ float sA[TPB], sB[TPB];
  const int tid = threadIdx.x;
  const int n = blockIdx.x;
  const float* p = hm + (size_t)n * NPIX;
  float v[16];
  float s = 0.0f, s2 = 0.0f;
  for (int i = 0; i < 16; i++) {
    const float x = p[tid + i * TPB];
    v[i] = x; s += x; s2 += x * x;
  }
  sA[tid] = s; sB[tid] = s2; __syncthreads();
  for (int st = 128; st; st >>= 1) {
    if (tid < st) { sA[tid] += sA[tid + st]; sB[tid] += sB[tid + st]; }
    __syncthreads();
  }
  const float S = sA[0], S2 = sB[0];
  const float mean = S / 4096.0f;
  const float var = (S2 - S * mean) / 4095.0f;
  if (tid == 0) std_hm[n] = sqrtf(fmaxf(var, 0.0f));
  float* o = hm_c + (size_t)n * NPIX;
  for (int i = 0; i < 16; i++) o[tid + i * TPB] = v[i] - mean;
}

// ---------------- field stats: s = std/(std+1e-6) over (3,h,w), ddof=1 --------------------
__global__ __launch_bounds__(TPB) void field_stats_kernel(const float* __restrict__ fields,
                                                          float* __restrict__ sf) {
  __shared__ float sA[TPB], sB[TPB];
  const int tid = threadIdx.x;
  const int n = blockIdx.x;
  const float* p = fields + (size_t)n * 3 * NPIX;
  float s = 0.0f, s2 = 0.0f;
  for (int i = tid; i < 3 * NPIX; i += TPB) {
    const float x = p[i];
    s += x; s2 += x * x;
  }
  sA[tid] = s; sB[tid] = s2; __syncthreads();
  for (int st = 128; st; st >>= 1) {
    if (tid < st) { sA[tid] += sA[tid + st]; sB[tid] += sB[tid + st]; }
    __syncthreads();
  }
  if (tid == 0) {
    const float S = sA[0], S2 = sB[0];
    const float var = (S2 - S * S / 12288.0f) / 12287.0f;
    const float sd = sqrtf(fmaxf(var, 0.0f));
    sf[n] = sd / (sd + 1e-6f);
  }
}

// ---------------- conv1: FFT conv of Hs with w1; epilogue coef + fields_new ---------------
__global__ __launch_bounds__(TPB) void conv1_kernel(const float* __restrict__ hm_c,
                                                    const float* __restrict__ fields,
                                                    const float* __restrict__ Wk,
                                                    float* __restrict__ out_fn) {
  __shared__ float re[128 * STRIDE];
  __shared__ float im[128 * STRIDE];
  __shared__ float twr[64], twi[64];
  const int tid = threadIdx.x;
  const int n = blockIdx.x;
  const int bv = n >> 4, l = n & 15;
  const float* h1 = hm_c + (size_t)(bv * NJ + c_P1[l]) * NPIX;
  const float* h0 = hm_c + (size_t)(bv * NJ + c_P0[l]) * NPIX;
  fft_init(re, im, twr, twi, tid);
  for (int i = tid; i < NPIX; i += TPB) {
    const int y = i >> 6, x = i & 63;
    re[y * STRIDE + x] = h1[i] - h0[i];
  }
  __syncthreads();
  fft_pass<false, true>(re, im, twr, twi, 64, tid);     // rows 64..127 are zero
  fft_pass<false, false>(re, im, twr, twi, 128, tid);
  fft_mult(re, im, Wk, tid);
  fft_pass<true, false>(re, im, twr, twi, 128, tid);
  fft_pass<true, true>(re, im, twr, twi, 64, tid);      // only need rows 0..63
  const float* f = fields + (size_t)n * 3 * NPIX;
  float* o = out_fn + (size_t)n * 3 * NPIX;
  for (int i = tid; i < NPIX; i += TPB) {
    const int y = i >> 6, x = i & 63;
    const int a = y * STRIDE + x;
    const float c1 = re[a];        // convs channel 1
    const float c0 = -im[a];       // convs channel 0
    const float f0 = f[i], f1 = f[NPIX + i], f2 = f[2 * NPIX + i];
    const float coef = fmaxf(0.0f, c0 * f0 + c1 * f1);
    o[i] = f0 * coef;
    o[NPIX + i] = f1 * coef;
    o[2 * NPIX + i] = f2 * coef;
  }
}

// ---------------- conv2: FFT conv of (f1 + i f0) with w2; scale by s ----------------------
__global__ __launch_bounds__(TPB) void conv2_kernel(const float* __restrict__ fields,
                                                    const float* __restrict__ sf,
                                                    const float* __restrict__ Wk,
                                                    float* __restrict__ fds) {
  __shared__ float re[128 * STRIDE];
  __shared__ float im[128 * STRIDE];
  __shared__ float twr[64], twi[64];
  const int tid = threadIdx.x;
  const int n = blockIdx.x;
  const float* f = fields + (size_t)n * 3 * NPIX;
  fft_init(re, im, twr, twi, tid);
  for (int i = tid; i < NPIX; i += TPB) {
    const int y = i >> 6, x = i & 63;
    re[y * STRIDE + x] = f[NPIX + i];   // channel 1
    im[y * STRIDE + x] = f[i];          // channel 0
  }
  __syncthreads();
  fft_pass<false, true>(re, im, twr, twi, 64, tid);
  fft_pass<false, false>(re, im, twr, twi, 128, tid);
  fft_mult(re, im, Wk, tid);
  fft_pass<true, false>(re, im, twr, twi, 128, tid);
  fft_pass<true, true>(re, im, twr, twi, 64, tid);
  const float s = sf[n];
  float* o = fds + (size_t)n * NPIX;
  for (int i = tid; i < NPIX; i += TPB) {
    const int y = i >> 6, x = i & 63;
    o[i] = re[y * STRIDE + x] * s;      // Re part = fds2jts, scaled
  }
}

// ---------------- reduction helpers -------------------------------------------------------
__device__ inline void reduce3(float& a, float& b, float& c,
                               float* s0, float* s1, float* s2, int tid) {
  s0[tid] = a; s1[tid] = b; s2[tid] = c; __syncthreads();
  for (int st = 128; st; st >>= 1) {
    if (tid < st) { s0[tid] += s0[tid + st]; s1[tid] += s1[tid + st]; s2[tid] += s2[tid + st]; }
    __syncthreads();
  }
  a = s0[0]; b = s1[0]; c = s2[0]; __syncthreads();
}

__device__ inline float reduce_max(float v, float* s0, int tid) {
  s0[tid] = v; __syncthreads();
  for (int st = 128; st; st >>= 1) {
    if (tid < st) s0[tid] = fmaxf(s0[tid], s0[tid + st]);
    __syncthreads();
  }
  const float r = s0[0]; __syncthreads();
  return r;
}

// ---------------- hms_new + normalize + soft-argmax + kps combine -------------------------
__global__ __launch_bounds__(TPB) void hms_kernel(const float* __restrict__ hm_c,
                                                  const float* __restrict__ std_hm,
                                                  const float* __restrict__ fds,
                                                  const float* __restrict__ confs,
                                                  const int* __restrict__ ishape,
                                                  const float* __restrict__ pth1p,
                                                  const float* __restrict__ pth2p,
                                                  float* __restrict__ out) {
  __shared__ float sA[TPB], sB[TPB], sC[TPB];
  const int tid = threadIdx.x;
  const int idx = blockIdx.x;           // bv*17 + j
  const int bv = idx / NJ, j = idx % NJ;
  const float* hp = hm_c + (size_t)idx * NPIX;
  const int pl = c_proxL[j], dl = c_distL[j];
  const float* fp = (pl >= 0) ? fds + (size_t)(bv * NL + pl) * NPIX : nullptr;
  const float* fd = (dl >= 0) ? fds + (size_t)(bv * NL + dl) * NPIX : nullptr;
  float ho[16], hn[16];
  float s = 0.0f, s2 = 0.0f, dummy = 0.0f;
  for (int i = 0; i < 16; i++) {
    const int px = tid + i * TPB;
    const float h = hp[px];
    ho[i] = h;
    float m = h;
    if (pl >= 0) m *= fmaxf(0.0f, -fp[px]);
    if (dl >= 0) m *= fmaxf(0.0f, fd[px]);
    hn[i] = m;
    s += m; s2 += m * m;
  }
  reduce3(s, s2, dummy, sA, sB, sC, tid);
  const float var = (s2 - s * s / 4096.0f) / 4095.0f;
  const float sdn = sqrtf(fmaxf(var, 0.0f));
  const float scale = std_hm[idx] / (sdn + 1e-6f);
  float* ohm = out + O_HM + (size_t)idx * NPIX;
  for (int i = 0; i < 16; i++) {
    hn[i] *= scale;
    ohm[tid + i * TPB] = hn[i];
  }
  // soft-argmax (old)
  float mo = -1e30f, mn = -1e30f;
  for (int i = 0; i < 16; i++) { mo = fmaxf(mo, ho[i]); mn = fmaxf(mn, hn[i]); }
  mo = reduce_max(mo, sA, tid);
  mn = reduce_max(mn, sA, tid);
  float So = 0.0f, Sxo = 0.0f, Syo = 0.0f;
  float Sn = 0.0f, Sxn = 0.0f, Syn = 0.0f;
  for (int i = 0; i < 16; i++) {
    const int px = tid + i * TPB;
    const float y = (float)(px >> 6), x = (float)(px & 63);
    const float eo = expf(kBeta * (ho[i] - mo));
    So += eo; Sxo += eo * y; Syo += eo * x;
    const float en = expf(kBeta * (hn[i] - mn));
    Sn += en; Sxn += en * y; Syn += en * x;
  }
  reduce3(So, Sxo, Syo, sA, sB, sC, tid);
  reduce3(Sn, Sxn, Syn, sA, sB, sC, tid);
  if (tid == 0) {
    const float sxs = (float)ishape[1] / 64.0f;
    const float sys = (float)ishape[0] / 64.0f;
    const float kxo = Sxo / So * sxs, kyo = Syo / So * sys;
    float kxn = Sxn / Sn * sxs, kyn = Syn / Sn * sys;
    if (kxn != kxn) kxn = kxo;
    if (kyn != kyn) kyn = kyo;
    const float ddx = kxn - kxo, ddy = kyn - kyo;
    const float disp = sqrtf(ddx * ddx + ddy * ddy);
    const float conf = confs[bv * (NL + NJ) + NL + j];
    const bool sel = (conf > pth1p[0]) && (disp < pth2p[0]);
    out[O_KPS + idx * 2 + 0] = sel ? kxn : kxo;
    out[O_KPS + idx * 2 + 1] = sel ? kyn : kyo;
  }
}

// ---------------- lvecs (comb_v) and lpts (comb_p) ----------------------------------------
__global__ __launch_bounds__(TPB) void lvec_kernel(const float* __restrict__ fields,
                                                   const int* __restrict__ ishape,
                                                   float* __restrict__ out) {
  __shared__ float sA[TPB], sB[TPB], sC[TPB];
  const int tid = threadIdx.x;
  const int n = blockIdx.x;
  const float* f = fields + (size_t)n * 3 * NPIX;
  float fn[16];
  float a0 = 0.0f, a1 = 0.0f, a2 = 0.0f;
  for (int i = 0; i < 16; i++) {
    const int px = tid + i * TPB;
    const float f0 = f[px], f1 = f[NPIX + px], f2 = f[2 * NPIX + px];
    const float nn = sqrtf(f0 * f0 + f1 * f1 + f2 * f2);
    fn[i] = nn;
    a0 += nn * f0; a1 += nn * f1; a2 += nn * f2;
  }
  reduce3(a0, a1, a2, sA, sB, sC, tid);
  float mx = -1e30f;
  for (int i = 0; i < 16; i++) mx = fmaxf(mx, fn[i]);
  mx = reduce_max(mx, sA, tid);
  float S = 0.0f, Sx = 0.0f, Sy = 0.0f;
  for (int i = 0; i < 16; i++) {
    const int px = tid + i * TPB;
    const float e = expf(kBeta * (fn[i] - mx));
    S += e; Sx += e * (float)(px >> 6); Sy += e * (float)(px & 63);
  }
  reduce3(S, Sx, Sy, sA, sB, sC, tid);
  if (tid == 0) {
    float nrm = sqrtf(a0 * a0 + a1 * a1 + a2 * a2);
    nrm = fmaxf(nrm, 1e-12f);
    out[O_CV + n * 3 + 0] = a0 / nrm;
    out[O_CV + n * 3 + 1] = a1 / nrm;
    out[O_CV + n * 3 + 2] = a2 / nrm;
    const float sxs = (float)ishape[1] / 64.0f;
    const float sys = (float)ishape[0] / 64.0f;
    out[O_CP + n * 2 + 0] = Sx / S * sxs;
    out[O_CP + n * 2 + 1] = Sy / S * sys;
  }
}

extern "C" void kernel_launch(void* const* d_in, const int* in_sizes, int n_in,
                              void* d_out, int out_size, void* d_ws, size_t ws_size,
                              hipStream_t stream) {
  const float* heat   = (const float*)d_in[0];
  const float* fields = (const float*)d_in[1];
  const int*   ishape = (const int*)d_in[5];
  const float* confs  = (const float*)d_in[6];
  const float* pth1   = (const float*)d_in[9];
  const float* pth2   = (const float*)d_in[10];
  float* out = (float*)d_out;
  float* ws = (float*)d_ws;
  float* hm_c   = ws + W_HMC;
  float* std_hm = ws + W_STDHM;
  float* sf     = ws + W_SF;
  float* fds    = ws + W_FDS;
  float* W1     = ws + W_W1;
  float* W2     = ws + W_W2;

  hipLaunchKernelGGL(hm_stats_kernel, dim3(NJP), dim3(TPB), 0, stream, heat, hm_c, std_hm);
  hipLaunchKernelGGL(field_stats_kernel, dim3(NIMG), dim3(TPB), 0, stream, fields, sf);
  hipLaunchKernelGGL(prep_kernel, dim3(2), dim3(TPB), 0, stream, W1, W2);
  hipLaunchKernelGGL(conv1_kernel, dim3(NIMG), dim3(TPB), 0, stream, hm_c, fields, W1, out + O_FN);
  hipLaunchKernelGGL(conv2_kernel, dim3(NIMG), dim3(TPB), 0, stream, fields, sf, W2, fds);
  hipLaunchKernelGGL(hms_kernel, dim3(NJP), dim3(TPB), 0, stream, hm_c, std_hm, fds, confs,
                     ishape, pth1, pth2, out);
  hipLaunchKernelGGL(lvec_kernel, dim3(NIMG), dim3(TPB), 0, stream, fields, ishape, out);
}

// Round 2
// 174.255 us; speedup vs baseline: 1.7171x; 1.7171x over previous
//
#include <hip/hip_runtime.h>
#include <math.h>

#define TPB 1024
#define HTPB 256
#define NPIX 4096
#define NJ 17
#define NL 16
static constexpr float kBeta = 100.0f;

// output layout (floats): kps(544) | comb_v(768) | comb_p(512) | fields_new(3145728) | hms_new(1114112)
#define O_KPS 0
#define O_CV 544
#define O_CP 1312
#define O_FN 1824
#define O_HM 3147552
// workspace layout (floats)
#define W_FDS 0               // 256*4096
#define W_MEAN 1048576        // 272
#define W_STD 1048848         // 272
#define W_SF 1049120          // 256
#define W_W1 1049376          // 16384 cplx
#define W_W2 1082144          // 16384 cplx

__device__ __constant__ int c_P0[16] = {0,1,2,0,4,5,0,7,8,9,8,11,12,8,14,15};
__device__ __constant__ int c_P1[16] = {1,2,3,4,5,6,7,8,9,10,11,12,13,14,15,16};
__device__ __constant__ int c_proxL[17] = {6,1,2,-1,4,5,-1,7,13,9,-1,11,12,-1,14,15,-1};
__device__ __constant__ int c_distL[17] = {-1,0,1,2,3,4,5,6,7,8,9,10,11,12,13,14,15};

using cplx = float2;
__device__ inline cplx cadd(cplx a, cplx b){ return {a.x+b.x, a.y+b.y}; }
__device__ inline cplx csub(cplx a, cplx b){ return {a.x-b.x, a.y-b.y}; }
__device__ inline cplx cmul(cplx a, cplx w){ return {a.x*w.x - a.y*w.y, a.x*w.y + a.y*w.x}; }
__device__ inline cplx cmulc(cplx a, cplx w){ return {a.x*w.x + a.y*w.y, a.y*w.x - a.x*w.y}; } // a*conj(w)

// swizzled complex address: element (row r, position-in-row c)
template<bool ROWS> __device__ inline int AD(int line, int p){
  return ROWS ? ((line<<7) | (p ^ (line & 15))) : ((p<<7) | (line ^ (p & 15)));
}

// radix-2 stage m=128. ZTOP: upper half (p>=64) is zero on input (forward only).
template<bool ROWS, bool INV, bool ZTOP, int NL_>
__device__ void pass_r2(cplx* S, const cplx* TW, int tid){
  constexpr int LOG2 = (NL_==128)?7:6;
  const int total = NL_*64;
  for (int idx = tid; idx < total; idx += TPB){
    const int line = idx & (NL_-1);
    const int b = idx >> LOG2;
    const cplx w = TW[b];
    const int a0 = AD<ROWS>(line, b);
    const int a1 = AD<ROWS>(line, b+64);
    if (ZTOP){
      const cplx u = S[a0];
      S[a1] = cmul(u, w);            // S[a0] unchanged (= u + 0)
    } else if (!INV){
      const cplx u = S[a0], v = S[a1];
      S[a0] = cadd(u,v);
      S[a1] = cmul(csub(u,v), w);
    } else {
      const cplx u = S[a0], t = cmulc(S[a1], w);
      S[a0] = cadd(u,t);
      S[a1] = csub(u,t);
    }
  }
  __syncthreads();
}

// radix-4 pass: forward = DIF stages (m=4Q, m=2Q); inverse = exact algebraic inverse (x4 scale)
template<bool ROWS, bool INV, int Q, int NL_>
__device__ void pass_r4(cplx* S, const cplx* TW, int tid){
  constexpr int LOG2 = (NL_==128)?7:6;
  constexpr int LQ = (Q==16)?4:((Q==4)?2:0);
  constexpr int S_ = 32/Q;
  const int total = NL_*32;
  for (int idx = tid; idx < total; idx += TPB){
    const int line = idx & (NL_-1);
    const int b = idx >> LOG2;
    const int j = b & (Q-1);
    const int blk = b >> LQ;
    const int p0 = blk*(4*Q) + j;
    const int a0 = AD<ROWS>(line, p0);
    const int a1 = AD<ROWS>(line, p0+Q);
    const int a2 = AD<ROWS>(line, p0+2*Q);
    const int a3 = AD<ROWS>(line, p0+3*Q);
    const cplx x0=S[a0], x1=S[a1], x2=S[a2], x3=S[a3];
    if constexpr (!INV){
      const cplx a = cadd(x0,x2), bb = csub(x0,x2);
      const cplx c = cadd(x1,x3), d = csub(x1,x3);
      const cplx dp = {d.y, -d.x};               // -i*d
      if constexpr (Q==1){
        S[a0] = cadd(a,c);  S[a1] = csub(a,c);
        S[a2] = cadd(bb,dp); S[a3] = csub(bb,dp);
      } else {
        const cplx w1 = TW[j*S_], w2 = TW[2*j*S_], w3 = TW[3*j*S_];
        S[a0] = cadd(a,c);
        S[a1] = cmul(csub(a,c), w2);
        S[a2] = cmul(cadd(bb,dp), w1);
        S[a3] = cmul(csub(bb,dp), w3);
      }
    } else {
      cplx z1, z2, z3;
      if constexpr (Q==1){ z1 = x1; z2 = x2; z3 = x3; }
      else {
        const cplx w1 = TW[j*S_], w2 = TW[2*j*S_], w3 = TW[3*j*S_];
        z1 = cmulc(x1,w2); z2 = cmulc(x2,w1); z3 = cmulc(x3,w3);
      }
      const cplx A = cadd(x0,z1), C = csub(x0,z1);
      const cplx B = cadd(z2,z3), D = csub(z2,z3);
      const cplx iD = {-D.y, D.x};               // i*D
      S[a0] = cadd(A,B);
      S[a1] = cadd(C,iD);
      S[a2] = csub(A,B);
      S[a3] = csub(C,iD);
    }
  }
  __syncthreads();
}

__device__ inline void tw_init(cplx* TW, int tid){
  if (tid < 96){
    float s, c;
    sincosf(-3.14159265358979323846f * (float)tid / 64.0f, &s, &c);
    TW[tid] = {c, s};
  }
  __syncthreads();
}

// forward 2D for conv inputs (spatial support 64x64; rows 64..127 / cols 64..127 implicitly zero)
__device__ inline void fft2d_fwd_conv(cplx* S, const cplx* TW, int tid){
  pass_r2<true,  false, true, 64 >(S, TW, tid);
  pass_r4<true,  false, 16,   64 >(S, TW, tid);
  pass_r4<true,  false, 4,    64 >(S, TW, tid);
  pass_r4<true,  false, 1,    64 >(S, TW, tid);
  pass_r2<false, false, true, 128>(S, TW, tid);
  pass_r4<false, false, 16,   128>(S, TW, tid);
  pass_r4<false, false, 4,    128>(S, TW, tid);
  pass_r4<false, false, 1,    128>(S, TW, tid);
}
__device__ inline void fft2d_inv_conv(cplx* S, const cplx* TW, int tid){
  pass_r4<false, true, 1,    128>(S, TW, tid);
  pass_r4<false, true, 4,    128>(S, TW, tid);
  pass_r4<false, true, 16,   128>(S, TW, tid);
  pass_r2<false, true, false,128>(S, TW, tid);
  pass_r4<true,  true, 1,    64 >(S, TW, tid);   // only spatial rows 0..63 needed
  pass_r4<true,  true, 4,    64 >(S, TW, tid);
  pass_r4<true,  true, 16,   64 >(S, TW, tid);
  pass_r2<true,  true, false,64 >(S, TW, tid);
}
__device__ inline void fft2d_fwd_full(cplx* S, const cplx* TW, int tid){
  pass_r2<true,  false, false,128>(S, TW, tid);
  pass_r4<true,  false, 16,   128>(S, TW, tid);
  pass_r4<true,  false, 4,    128>(S, TW, tid);
  pass_r4<true,  false, 1,    128>(S, TW, tid);
  pass_r2<false, false, false,128>(S, TW, tid);
  pass_r4<false, false, 16,   128>(S, TW, tid);
  pass_r4<false, false, 4,    128>(S, TW, tid);
  pass_r4<false, false, 1,    128>(S, TW, tid);
}

// ---------------- reductions ----------------
template<int N>
__device__ inline void reduce3n(float& a, float& b, float& c,
                                float* s0, float* s1, float* s2, int tid){
  s0[tid]=a; s1[tid]=b; s2[tid]=c; __syncthreads();
  for (int st = N/2; st; st >>= 1){
    if (tid < st){ s0[tid]+=s0[tid+st]; s1[tid]+=s1[tid+st]; s2[tid]+=s2[tid+st]; }
    __syncthreads();
  }
  a=s0[0]; b=s1[0]; c=s2[0]; __syncthreads();
}
template<int N>
__device__ inline float reduce_maxn(float v, float* s0, int tid){
  s0[tid]=v; __syncthreads();
  for (int st = N/2; st; st >>= 1){
    if (tid < st) s0[tid] = fmaxf(s0[tid], s0[tid+st]);
    __syncthreads();
  }
  const float r = s0[0]; __syncthreads();
  return r;
}

// ---------------- pre: hm stats | field stats + lvec/lpt | kernel FFT prep ----------------
__global__ __launch_bounds__(TPB,1) void pre_kernel(const float* __restrict__ heat,
                                                    const float* __restrict__ fields,
                                                    const int* __restrict__ ishape,
                                                    float* __restrict__ mean_hm,
                                                    float* __restrict__ std_hm,
                                                    float* __restrict__ sf,
                                                    float* __restrict__ W1,
                                                    float* __restrict__ W2,
                                                    float* __restrict__ out){
  __shared__ cplx S[16384];
  __shared__ cplx TW[96];
  __shared__ float sA[TPB], sB[TPB], sC[TPB];
  const int tid = threadIdx.x;
  const int blk = blockIdx.x;
  if (blk < 272){
    const float* p = heat + (size_t)blk * NPIX;
    float s = 0.0f, s2 = 0.0f, d = 0.0f;
    for (int i = 0; i < 4; i++){
      const float x = p[tid + i*TPB];
      s += x; s2 += x*x;
    }
    reduce3n<TPB>(s, s2, d, sA, sB, sC, tid);
    if (tid == 0){
      const float mean = s / 4096.0f;
      const float var = (s2 - s*mean) / 4095.0f;
      mean_hm[blk] = mean;
      std_hm[blk] = sqrtf(fmaxf(var, 0.0f));
    }
  } else if (blk < 528){
    const int m = blk - 272;
    const float* f = fields + (size_t)m * 3 * NPIX;
    float s1 = 0.0f, s2 = 0.0f;
    float a0 = 0.0f, a1 = 0.0f, a2 = 0.0f;
    float fn[4];
    for (int i = 0; i < 4; i++){
      const int px = tid + i*TPB;
      const float f0 = f[px], f1 = f[NPIX+px], f2 = f[2*NPIX+px];
      s1 += f0+f1+f2; s2 += f0*f0+f1*f1+f2*f2;
      const float nn = sqrtf(f0*f0 + f1*f1 + f2*f2);
      fn[i] = nn;
      a0 += nn*f0; a1 += nn*f1; a2 += nn*f2;
    }
    {
      float t1 = s1, t2 = s2, t3 = 0.0f;
      reduce3n<TPB>(t1, t2, t3, sA, sB, sC, tid);
      if (tid == 0){
        const float var = (t2 - t1*t1/12288.0f) / 12287.0f;
        const float sd = sqrtf(fmaxf(var, 0.0f));
        sf[m] = sd / (sd + 1e-6f);
      }
    }
    reduce3n<TPB>(a0, a1, a2, sA, sB, sC, tid);
    float mx = fmaxf(fmaxf(fn[0],fn[1]), fmaxf(fn[2],fn[3]));
    mx = reduce_maxn<TPB>(mx, sA, tid);
    float Sm = 0.0f, Sx = 0.0f, Sy = 0.0f;
    for (int i = 0; i < 4; i++){
      const int px = tid + i*TPB;
      const float e = expf(kBeta * (fn[i] - mx));
      Sm += e; Sx += e * (float)(px>>6); Sy += e * (float)(px&63);
    }
    reduce3n<TPB>(Sm, Sx, Sy, sA, sB, sC, tid);
    if (tid == 0){
      float nrm = sqrtf(a0*a0 + a1*a1 + a2*a2);
      nrm = fmaxf(nrm, 1e-12f);
      out[O_CV + m*3 + 0] = a0/nrm;
      out[O_CV + m*3 + 1] = a1/nrm;
      out[O_CV + m*3 + 2] = a2/nrm;
      const float sxs = (float)ishape[1] / 64.0f;
      const float sys = (float)ishape[0] / 64.0f;
      out[O_CP + m*2 + 0] = Sx/Sm * sxs;
      out[O_CP + m*2 + 1] = Sy/Sm * sys;
    }
  } else {
    const int which = blk - 528;
    tw_init(TW, tid);
    for (int i = tid; i < 16384; i += TPB){
      const int r = i >> 7, c = i & 127;
      const int dy = (r < 64) ? r : r - 128;
      const int dx = (c < 64) ? c : c - 128;
      float a, b;
      if (which == 0){ a = 1.0f - (float)dy; b = 1.0f - (float)dx; }
      else           { a = 1.0f + (float)dy; b = 1.0f + (float)dx; }
      const float den = a*a + b*b;
      float vr = 0.0f, vi = 0.0f;
      if (r != 64 && c != 64 && den > 0.0f){
        const float inv = 1.0f/den;
        vr = a*inv; vi = -b*inv;
      }
      S[(r<<7) | (c ^ (r & 15))] = {vr, vi};
    }
    __syncthreads();
    fft2d_fwd_full(S, TW, tid);
    float2* Wo = (float2*)((which == 0) ? W1 : W2);
    const float scl = 1.0f / 16384.0f;
    for (int i = tid; i < 16384; i += TPB) Wo[i] = {S[i].x*scl, S[i].y*scl};
  }
}

// ---------------- conv: blocks 0..255 conv1, 256..511 conv2 ----------------
__global__ __launch_bounds__(TPB,1) void conv_kernel(const float* __restrict__ heat,
                                                     const float* __restrict__ mean_hm,
                                                     const float* __restrict__ fields,
                                                     const float* __restrict__ sf,
                                                     const float* __restrict__ W1g,
                                                     const float* __restrict__ W2g,
                                                     float* __restrict__ out_fn,
                                                     float* __restrict__ fds){
  __shared__ cplx S[16384];
  __shared__ cplx TW[96];
  const int tid = threadIdx.x;
  const int n = blockIdx.x;
  tw_init(TW, tid);
  if (n < 256){
    const int bv = n >> 4, l = n & 15;
    const int j1 = bv*NJ + c_P1[l], j0 = bv*NJ + c_P0[l];
    const float* h1 = heat + (size_t)j1 * NPIX;
    const float* h0 = heat + (size_t)j0 * NPIX;
    const float dm = mean_hm[j1] - mean_hm[j0];
    for (int i = tid; i < NPIX; i += TPB){
      const int y = i >> 6, x = i & 63;
      S[(y<<7) | (x ^ (y & 15))] = {h1[i] - h0[i] - dm, 0.0f};
    }
    __syncthreads();
    fft2d_fwd_conv(S, TW, tid);
    const float2* Wg = (const float2*)W1g;
    for (int i = tid; i < 16384; i += TPB) S[i] = cmul(S[i], Wg[i]);
    __syncthreads();
    fft2d_inv_conv(S, TW, tid);
    const float* f = fields + (size_t)n * 3 * NPIX;
    float* o = out_fn + (size_t)n * 3 * NPIX;
    for (int i = tid; i < NPIX; i += TPB){
      const int y = i >> 6, x = i & 63;
      const cplx v = S[(y<<7) | (x ^ (y & 15))];
      const float c1 = v.x, c0 = -v.y;
      const float f0 = f[i], f1 = f[NPIX+i], f2 = f[2*NPIX+i];
      const float coef = fmaxf(0.0f, c0*f0 + c1*f1);
      o[i] = f0*coef; o[NPIX+i] = f1*coef; o[2*NPIX+i] = f2*coef;
    }
  } else {
    const int m = n - 256;
    const float* f = fields + (size_t)m * 3 * NPIX;
    for (int i = tid; i < NPIX; i += TPB){
      const int y = i >> 6, x = i & 63;
      S[(y<<7) | (x ^ (y & 15))] = {f[NPIX+i], f[i]};   // (ch1, ch0)
    }
    __syncthreads();
    fft2d_fwd_conv(S, TW, tid);
    const float2* Wg = (const float2*)W2g;
    for (int i = tid; i < 16384; i += TPB) S[i] = cmul(S[i], Wg[i]);
    __syncthreads();
    fft2d_inv_conv(S, TW, tid);
    const float s = sf[m];
    float* o = fds + (size_t)m * NPIX;
    for (int i = tid; i < NPIX; i += TPB){
      const int y = i >> 6, x = i & 63;
      o[i] = S[(y<<7) | (x ^ (y & 15))].x * s;
    }
  }
}

// ---------------- hms_new + normalize + soft-argmax + kps combine ----------------
__global__ __launch_bounds__(HTPB) void hms_kernel(const float* __restrict__ heat,
                                                   const float* __restrict__ mean_hm,
                                                   const float* __restrict__ std_hm,
                                                   const float* __restrict__ fds,
                                                   const float* __restrict__ confs,
                                                   const int* __restrict__ ishape,
                                                   const float* __restrict__ pth1p,
                                                   const float* __restrict__ pth2p,
                                                   float* __restrict__ out){
  __shared__ float sA[HTPB], sB[HTPB], sC[HTPB];
  const int tid = threadIdx.x;
  const int idx = blockIdx.x;           // bv*17 + j
  const int bv = idx / NJ, j = idx % NJ;
  const float* hp = heat + (size_t)idx * NPIX;
  const float mh = mean_hm[idx];
  const int pl = c_proxL[j], dl = c_distL[j];
  const float* fp = (pl >= 0) ? fds + (size_t)(bv*NL + pl) * NPIX : nullptr;
  const float* fd = (dl >= 0) ? fds + (size_t)(bv*NL + dl) * NPIX : nullptr;
  float ho[16], hn[16];
  float s = 0.0f, s2 = 0.0f, dummy = 0.0f;
  for (int i = 0; i < 16; i++){
    const int px = tid + i*HTPB;
    const float h = hp[px] - mh;
    ho[i] = h;
    float m = h;
    if (pl >= 0) m *= fmaxf(0.0f, -fp[px]);
    if (dl >= 0) m *= fmaxf(0.0f, fd[px]);
    hn[i] = m;
    s += m; s2 += m*m;
  }
  reduce3n<HTPB>(s, s2, dummy, sA, sB, sC, tid);
  const float var = (s2 - s*s/4096.0f) / 4095.0f;
  const float sdn = sqrtf(fmaxf(var, 0.0f));
  const float scale = std_hm[idx] / (sdn + 1e-6f);
  float* ohm = out + O_HM + (size_t)idx * NPIX;
  for (int i = 0; i < 16; i++){
    hn[i] *= scale;
    ohm[tid + i*HTPB] = hn[i];
  }
  float mo = -1e30f, mn = -1e30f;
  for (int i = 0; i < 16; i++){ mo = fmaxf(mo, ho[i]); mn = fmaxf(mn, hn[i]); }
  mo = reduce_maxn<HTPB>(mo, sA, tid);
  mn = reduce_maxn<HTPB>(mn, sA, tid);
  float So = 0.0f, Sxo = 0.0f, Syo = 0.0f;
  float Sn = 0.0f, Sxn = 0.0f, Syn = 0.0f;
  for (int i = 0; i < 16; i++){
    const int px = tid + i*HTPB;
    const float y = (float)(px >> 6), x = (float)(px & 63);
    const float eo = expf(kBeta * (ho[i] - mo));
    So += eo; Sxo += eo*y; Syo += eo*x;
    const float en = expf(kBeta * (hn[i] - mn));
    Sn += en; Sxn += en*y; Syn += en*x;
  }
  reduce3n<HTPB>(So, Sxo, Syo, sA, sB, sC, tid);
  reduce3n<HTPB>(Sn, Sxn, Syn, sA, sB, sC, tid);
  if (tid == 0){
    const float sxs = (float)ishape[1] / 64.0f;
    const float sys = (float)ishape[0] / 64.0f;
    const float kxo = Sxo/So * sxs, kyo = Syo/So * sys;
    float kxn = Sxn/Sn * sxs, kyn = Syn/Sn * sys;
    if (kxn != kxn) kxn = kxo;
    if (kyn != kyn) kyn = kyo;
    const float ddx = kxn - kxo, ddy = kyn - kyo;
    const float disp = sqrtf(ddx*ddx + ddy*ddy);
    const float conf = confs[bv*(NL+NJ) + NL + j];
    const bool sel = (conf > pth1p[0]) && (disp < pth2p[0]);
    out[O_KPS + idx*2 + 0] = sel ? kxn : kxo;
    out[O_KPS + idx*2 + 1] = sel ? kyn : kyo;
  }
}

extern "C" void kernel_launch(void* const* d_in, const int* in_sizes, int n_in,
                              void* d_out, int out_size, void* d_ws, size_t ws_size,
                              hipStream_t stream) {
  const float* heat   = (const float*)d_in[0];
  const float* fields = (const float*)d_in[1];
  const int*   ishape = (const int*)d_in[5];
  const float* confs  = (const float*)d_in[6];
  const float* pth1   = (const float*)d_in[9];
  const float* pth2   = (const float*)d_in[10];
  float* out = (float*)d_out;
  float* ws = (float*)d_ws;
  float* fds     = ws + W_FDS;
  float* mean_hm = ws + W_MEAN;
  float* std_hm  = ws + W_STD;
  float* sf      = ws + W_SF;
  float* W1      = ws + W_W1;
  float* W2      = ws + W_W2;

  hipLaunchKernelGGL(pre_kernel, dim3(530), dim3(TPB), 0, stream,
                     heat, fields, ishape, mean_hm, std_hm, sf, W1, W2, out);
  hipLaunchKernelGGL(conv_kernel, dim3(512), dim3(TPB), 0, stream,
                     heat, mean_hm, fields, sf, W1, W2, out + O_FN, fds);
  hipLaunchKernelGGL(hms_kernel, dim3(272), dim3(HTPB), 0, stream,
                     heat, mean_hm, std_hm, fds, confs, ishape, pth1, pth2, out);
}

// Round 3
// 159.762 us; speedup vs baseline: 1.8728x; 1.0907x over previous
//
#include <hip/hip_runtime.h>
#include <math.h>

#define TPB 1024
#define HTPB 256
#define NPIX 4096
#define NJ 17
#define NL 16
static constexpr float kBeta = 100.0f;
static constexpr float S2H = 0.70710678118654752f;

// output layout (floats): kps(544) | comb_v(768) | comb_p(512) | fields_new(3145728) | hms_new(1114112)
#define O_KPS 0
#define O_CV 544
#define O_CP 1312
#define O_FN 1824
#define O_HM 3147552
// workspace layout (floats)
#define W_FDS 0               // 256*4096
#define W_MEAN 1048576        // 272
#define W_STD 1048848         // 272
#define W_SF 1049120          // 256
#define W_W1 1049376          // 16384 cplx
#define W_W2 1082144          // 16384 cplx

__device__ __constant__ int c_P0[16] = {0,1,2,0,4,5,0,7,8,9,8,11,12,8,14,15};
__device__ __constant__ int c_P1[16] = {1,2,3,4,5,6,7,8,9,10,11,12,13,14,15,16};
__device__ __constant__ int c_proxL[17] = {6,1,2,-1,4,5,-1,7,13,9,-1,11,12,-1,14,15,-1};
__device__ __constant__ int c_distL[17] = {-1,0,1,2,3,4,5,6,7,8,9,10,11,12,13,14,15};

using cplx = float2;
__device__ inline cplx cadd(cplx a, cplx b){ return {a.x+b.x, a.y+b.y}; }
__device__ inline cplx csub(cplx a, cplx b){ return {a.x-b.x, a.y-b.y}; }
__device__ inline cplx cmul(cplx a, cplx w){ return {a.x*w.x - a.y*w.y, a.x*w.y + a.y*w.x}; }
__device__ inline cplx cmulc(cplx a, cplx w){ return {a.x*w.x + a.y*w.y, a.y*w.x - a.x*w.y}; }

// w_128^{br3(p)} and w_16^{br3(p)}, br3 = {0,4,2,6,1,5,3,7}
__device__ __constant__ float2 W128BR[8] = {
  {1.f,0.f},
  {0.98078528040323044913f,-0.19509032201612826785f},
  {0.99518472667219688624f,-0.09801714032956060199f},
  {0.95694033573220886494f,-0.29028467725446236764f},
  {0.99879545620517239271f,-0.04906767432741801425f},
  {0.97003125319454399260f,-0.24298017990326388995f},
  {0.98917650996478097345f,-0.14673047445536175166f},
  {0.94154406518302077841f,-0.33688985339222005069f}
};
__device__ __constant__ float2 W16BR[8] = {
  {1.f,0.f},
  {0.f,-1.f},
  {0.70710678118654752440f,-0.70710678118654752440f},
  {-0.70710678118654752440f,-0.70710678118654752440f},
  {0.92387953251128675613f,-0.38268343236508977173f},
  {-0.38268343236508977173f,-0.92387953251128675613f},
  {0.38268343236508977173f,-0.92387953251128675613f},
  {-0.92387953251128675613f,-0.38268343236508977173f}
};

// -------- 8-point DFT (radix-2 DIF, output bit-reversed); inverse = exact inverse (gain 8) ----
__device__ inline void bf8_tail(cplx t0, cplx t1, cplx t2, cplx t3,
                                cplx t4, cplx t5, cplx t6, cplx t7, cplx x[8]){
  cplx u0=cadd(t0,t2), u2=csub(t0,t2);
  cplx u1=cadd(t1,t3), d13=csub(t1,t3);
  cplx u3={d13.y,-d13.x};
  cplx u4=cadd(t4,t6), u6=csub(t4,t6);
  cplx u5=cadd(t5,t7), d57=csub(t5,t7);
  cplx u7={d57.y,-d57.x};
  x[0]=cadd(u0,u1); x[1]=csub(u0,u1);
  x[2]=cadd(u2,u3); x[3]=csub(u2,u3);
  x[4]=cadd(u4,u5); x[5]=csub(u4,u5);
  x[6]=cadd(u6,u7); x[7]=csub(u6,u7);
}
__device__ inline void bf8_fwd(cplx x[8]){
  cplx t0=cadd(x[0],x[4]), d4=csub(x[0],x[4]);
  cplx t1=cadd(x[1],x[5]), d5=csub(x[1],x[5]);
  cplx t2=cadd(x[2],x[6]), d6=csub(x[2],x[6]);
  cplx t3=cadd(x[3],x[7]), d7=csub(x[3],x[7]);
  cplx t5={S2H*(d5.x+d5.y), S2H*(d5.y-d5.x)};
  cplx t6={d6.y,-d6.x};
  cplx t7={S2H*(d7.y-d7.x), -S2H*(d7.x+d7.y)};
  bf8_tail(t0,t1,t2,t3,d4,t5,t6,t7,x);
}
__device__ inline void bf8_fwd_z(cplx x[8]){   // x[4..7] == 0 implicitly
  cplx t5={S2H*(x[1].x+x[1].y), S2H*(x[1].y-x[1].x)};
  cplx t6={x[2].y,-x[2].x};
  cplx t7={S2H*(x[3].y-x[3].x), -S2H*(x[3].x+x[3].y)};
  bf8_tail(x[0],x[1],x[2],x[3],x[0],t5,t6,t7,x);
}
__device__ inline void bf8_inv(cplx y[8]){
  cplx u0=cadd(y[0],y[1]), u1=csub(y[0],y[1]);
  cplx u2=cadd(y[2],y[3]), u3=csub(y[2],y[3]);
  cplx u4=cadd(y[4],y[5]), u5=csub(y[4],y[5]);
  cplx u6=cadd(y[6],y[7]), u7=csub(y[6],y[7]);
  cplx t0=cadd(u0,u2), t2=csub(u0,u2);
  cplx iu3={-u3.y,u3.x};
  cplx t1=cadd(u1,iu3), t3=csub(u1,iu3);
  cplx t4=cadd(u4,u6), t6=csub(u4,u6);
  cplx iu7={-u7.y,u7.x};
  cplx t5=cadd(u5,iu7), t7=csub(u5,iu7);
  y[0]=cadd(t0,t4); y[4]=csub(t0,t4);
  cplx w5={S2H*(t5.x-t5.y), S2H*(t5.x+t5.y)};
  y[1]=cadd(t1,w5); y[5]=csub(t1,w5);
  cplx w6={-t6.y,t6.x};
  y[2]=cadd(t2,w6); y[6]=csub(t2,w6);
  cplx w7={-S2H*(t7.x+t7.y), S2H*(t7.x-t7.y)};
  y[3]=cadd(t3,w7); y[7]=csub(t3,w7);
}

// -------- 16-point DFT in registers (8x2); inverse = exact inverse (gain 16) ----------------
__device__ inline void fft16_fwd(cplx z[16]){
  cplx e[8], o[8];
  #pragma unroll
  for (int t=0;t<8;t++){ e[t]=z[2*t]; o[t]=z[2*t+1]; }
  bf8_fwd(e); bf8_fwd(o);
  #pragma unroll
  for (int p=0;p<8;p++){
    cplx vo = cmul(o[p], W16BR[p]);
    z[2*p]   = cadd(e[p], vo);
    z[2*p+1] = csub(e[p], vo);
  }
}
__device__ inline void fft16_inv(cplx z[16]){
  cplx e[8], o[8];
  #pragma unroll
  for (int p=0;p<8;p++){
    cplx a=z[2*p], b=z[2*p+1];
    e[p] = cadd(a,b);
    o[p] = cmulc(csub(a,b), W16BR[p]);
  }
  bf8_inv(e); bf8_inv(o);
  #pragma unroll
  for (int t=0;t<8;t++){ z[2*t]=e[t]; z[2*t+1]=o[t]; }
}

// A[p] = w_128^{j*br3(p)} via chain from TW[j]
__device__ inline void twchainA(const cplx* TW, int j, cplx A[8]){
  cplx W1 = TW[j];
  cplx W2 = cmul(W1,W1);
  cplx W4 = cmul(W2,W2);
  cplx W6 = cmul(W4,W2);
  A[0] = {1.f,0.f}; A[1] = W4; A[2] = W2; A[3] = W6;
  A[4] = W1; A[5] = cmul(W4,W1); A[6] = cmul(W2,W1); A[7] = cmul(W6,W1);
}

// physical f4-slot for logical (row y, slot-in-row m):
__device__ inline int PH(int y, int m){ return (y<<6) | ((m ^ ((y&7)*9)) & 63); }

// ---------------- passes (S4 = float4[8192], 128x64 slots) --------------------------------
template<int NLINES, bool ZT>
__device__ void row_s1_fwd(float4* S4, const cplx* TW, int tid){
  if (tid < NLINES*8){
    const int L = tid>>3, m = tid&7;
    cplx xe[8], xo[8];
    #pragma unroll
    for (int t=0; t<(ZT?4:8); t++){
      float4 v = S4[PH(L, m+8*t)];
      xe[t]={v.x,v.y}; xo[t]={v.z,v.w};
    }
    if (ZT){ bf8_fwd_z(xe); bf8_fwd_z(xo); } else { bf8_fwd(xe); bf8_fwd(xo); }
    cplx A[8]; twchainA(TW, 2*m, A);
    #pragma unroll
    for (int p=0;p<8;p++){
      cplx B = cmul(A[p], W128BR[p]);
      cplx ve = cmul(xe[p], A[p]);
      cplx vo = cmul(xo[p], B);
      S4[PH(L, m+8*p)] = {ve.x, ve.y, vo.x, vo.y};
    }
  }
  __syncthreads();
}
__device__ void row_s1_inv(float4* S4, const cplx* TW, int tid){   // 64 lines, write t<4
  if (tid < 512){
    const int L = tid>>3, m = tid&7;
    cplx xe[8], xo[8];
    #pragma unroll
    for (int p=0;p<8;p++){
      float4 v = S4[PH(L, m+8*p)];
      xe[p]={v.x,v.y}; xo[p]={v.z,v.w};
    }
    cplx A[8]; twchainA(TW, 2*m, A);
    #pragma unroll
    for (int p=0;p<8;p++){
      cplx B = cmul(A[p], W128BR[p]);
      xe[p] = cmulc(xe[p], A[p]);
      xo[p] = cmulc(xo[p], B);
    }
    bf8_inv(xe); bf8_inv(xo);
    #pragma unroll
    for (int t=0;t<4;t++)
      S4[PH(L, m+8*t)] = {xe[t].x, xe[t].y, xo[t].x, xo[t].y};
  }
  __syncthreads();
}
template<int NLINES>
__device__ void row_s2_fwd(float4* S4, int tid){
  if (tid < NLINES*8){
    const int L = tid>>3, jb = tid&7;
    cplx z[16];
    #pragma unroll
    for (int k=0;k<8;k++){
      float4 v = S4[PH(L, jb*8+k)];
      z[2*k]={v.x,v.y}; z[2*k+1]={v.z,v.w};
    }
    fft16_fwd(z);
    #pragma unroll
    for (int k=0;k<8;k++)
      S4[PH(L, jb*8+k)] = {z[2*k].x, z[2*k].y, z[2*k+1].x, z[2*k+1].y};
  }
  __syncthreads();
}
__device__ void row_s2_inv(float4* S4, int tid){   // 64 lines
  if (tid < 512){
    const int L = tid>>3, jb = tid&7;
    cplx z[16];
    #pragma unroll
    for (int k=0;k<8;k++){
      float4 v = S4[PH(L, jb*8+k)];
      z[2*k]={v.x,v.y}; z[2*k+1]={v.z,v.w};
    }
    fft16_inv(z);
    #pragma unroll
    for (int k=0;k<8;k++)
      S4[PH(L, jb*8+k)] = {z[2*k].x, z[2*k].y, z[2*k+1].x, z[2*k+1].y};
  }
  __syncthreads();
}
template<bool ZT>
__device__ void col_s1_fwd(float4* S4, const cplx* TW, int tid){
  const int cp = tid & 63, yj = tid >> 6;           // 1024 units
  const int sl = (cp ^ ((yj&7)*9)) & 63;
  cplx xe[8], xo[8];
  #pragma unroll
  for (int t=0; t<(ZT?4:8); t++){
    float4 v = S4[((yj+16*t)<<6) | sl];
    xe[t]={v.x,v.y}; xo[t]={v.z,v.w};
  }
  if (ZT){ bf8_fwd_z(xe); bf8_fwd_z(xo); } else { bf8_fwd(xe); bf8_fwd(xo); }
  cplx A[8]; twchainA(TW, yj, A);
  #pragma unroll
  for (int p=0;p<8;p++){
    cplx ve = cmul(xe[p], A[p]);
    cplx vo = cmul(xo[p], A[p]);
    S4[((yj+16*p)<<6) | sl] = {ve.x, ve.y, vo.x, vo.y};
  }
  __syncthreads();
}
__device__ void col_s1_inv(float4* S4, const cplx* TW, int tid){   // write t<4 (rows y<64)
  const int cp = tid & 63, yj = tid >> 6;
  const int sl = (cp ^ ((yj&7)*9)) & 63;
  cplx xe[8], xo[8];
  #pragma unroll
  for (int p=0;p<8;p++){
    float4 v = S4[((yj+16*p)<<6) | sl];
    xe[p]={v.x,v.y}; xo[p]={v.z,v.w};
  }
  cplx A[8]; twchainA(TW, yj, A);
  #pragma unroll
  for (int p=0;p<8;p++){
    xe[p] = cmulc(xe[p], A[p]);
    xo[p] = cmulc(xo[p], A[p]);
  }
  bf8_inv(xe); bf8_inv(xo);
  #pragma unroll
  for (int t=0;t<4;t++)
    S4[((yj+16*t)<<6) | sl] = {xe[t].x, xe[t].y, xo[t].x, xo[t].y};
  __syncthreads();
}
// fused: col s2 forward -> pointwise * Wg -> col s2 inverse, all in registers
__device__ void col_s2_fused(float4* S4, const cplx* __restrict__ Wg, int tid){
  cplx* Sc = (cplx*)S4;
  const int c = tid & 127, r = tid >> 7;
  const int ch = c & 1, cp = c >> 1;
  int ad[16];
  cplx z[16];
  #pragma unroll
  for (int i=0;i<16;i++){
    const int y = 16*r + i;
    ad[i] = ((((y<<6) | ((cp ^ ((y&7)*9)) & 63)) << 1) | ch);
    z[i] = Sc[ad[i]];
  }
  fft16_fwd(z);
  #pragma unroll
  for (int i=0;i<16;i++) z[i] = cmul(z[i], Wg[(16*r+i)*128 + c]);
  fft16_inv(z);
  #pragma unroll
  for (int i=0;i<16;i++) Sc[ad[i]] = z[i];
  __syncthreads();
}
// prep: col s2 forward, store spectrum directly to global (scaled)
__device__ void col_s2_fwd_store(float4* S4, cplx* __restrict__ Wo, int tid){
  cplx* Sc = (cplx*)S4;
  const int c = tid & 127, r = tid >> 7;
  const int ch = c & 1, cp = c >> 1;
  cplx z[16];
  #pragma unroll
  for (int i=0;i<16;i++){
    const int y = 16*r + i;
    z[i] = Sc[(((y<<6) | ((cp ^ ((y&7)*9)) & 63)) << 1) | ch];
  }
  fft16_fwd(z);
  const float scl = 1.0f / 16384.0f;
  #pragma unroll
  for (int i=0;i<16;i++) Wo[(16*r+i)*128 + c] = {z[i].x*scl, z[i].y*scl};
}

// ---------------- reductions ----------------
template<int N>
__device__ inline void reduce3n(float& a, float& b, float& c,
                                float* s0, float* s1, float* s2, int tid){
  s0[tid]=a; s1[tid]=b; s2[tid]=c; __syncthreads();
  for (int st = N/2; st; st >>= 1){
    if (tid < st){ s0[tid]+=s0[tid+st]; s1[tid]+=s1[tid+st]; s2[tid]+=s2[tid+st]; }
    __syncthreads();
  }
  a=s0[0]; b=s1[0]; c=s2[0]; __syncthreads();
}
template<int N>
__device__ inline float reduce_maxn(float v, float* s0, int tid){
  s0[tid]=v; __syncthreads();
  for (int st = N/2; st; st >>= 1){
    if (tid < st) s0[tid] = fmaxf(s0[tid], s0[tid+st]);
    __syncthreads();
  }
  const float r = s0[0]; __syncthreads();
  return r;
}

__device__ inline cplx wval(int r, int c, int which){
  const int dy = (r<64)? r : r-128;
  const int dx = (c<64)? c : c-128;
  float a, b;
  if (which==0){ a = 1.f-(float)dy; b = 1.f-(float)dx; }
  else         { a = 1.f+(float)dy; b = 1.f+(float)dx; }
  const float den = a*a + b*b;
  if (r==64 || c==64 || den<=0.f) return {0.f,0.f};
  const float inv = 1.f/den;
  return {a*inv, -b*inv};
}

// ---------------- pre: hm stats | field stats + lvec/lpt | kernel FFT prep ----------------
__global__ __launch_bounds__(TPB,4) void pre_kernel(const float* __restrict__ heat,
                                                    const float* __restrict__ fields,
                                                    const int* __restrict__ ishape,
                                                    float* __restrict__ mean_hm,
                                                    float* __restrict__ std_hm,
                                                    float* __restrict__ sf,
                                                    float* __restrict__ W1,
                                                    float* __restrict__ W2,
                                                    float* __restrict__ out){
  __shared__ float4 S4[8192];
  __shared__ cplx TW[128];
  __shared__ float sA[TPB], sB[TPB], sC[TPB];
  const int tid = threadIdx.x;
  const int blk = blockIdx.x;
  if (blk < 272){
    const float* p = heat + (size_t)blk * NPIX;
    float s = 0.0f, s2 = 0.0f, d = 0.0f;
    for (int i = 0; i < 4; i++){
      const float x = p[tid + i*TPB];
      s += x; s2 += x*x;
    }
    reduce3n<TPB>(s, s2, d, sA, sB, sC, tid);
    if (tid == 0){
      const float mean = s / 4096.0f;
      const float var = (s2 - s*mean) / 4095.0f;
      mean_hm[blk] = mean;
      std_hm[blk] = sqrtf(fmaxf(var, 0.0f));
    }
  } else if (blk < 528){
    const int m = blk - 272;
    const float* f = fields + (size_t)m * 3 * NPIX;
    float s1 = 0.0f, s2 = 0.0f;
    float a0 = 0.0f, a1 = 0.0f, a2 = 0.0f;
    float fn[4];
    for (int i = 0; i < 4; i++){
      const int px = tid + i*TPB;
      const float f0 = f[px], f1 = f[NPIX+px], f2 = f[2*NPIX+px];
      s1 += f0+f1+f2; s2 += f0*f0+f1*f1+f2*f2;
      const float nn = sqrtf(f0*f0 + f1*f1 + f2*f2);
      fn[i] = nn;
      a0 += nn*f0; a1 += nn*f1; a2 += nn*f2;
    }
    {
      float t1 = s1, t2 = s2, t3 = 0.0f;
      reduce3n<TPB>(t1, t2, t3, sA, sB, sC, tid);
      if (tid == 0){
        const float var = (t2 - t1*t1/12288.0f) / 12287.0f;
        const float sd = sqrtf(fmaxf(var, 0.0f));
        sf[m] = sd / (sd + 1e-6f);
      }
    }
    reduce3n<TPB>(a0, a1, a2, sA, sB, sC, tid);
    float mx = fmaxf(fmaxf(fn[0],fn[1]), fmaxf(fn[2],fn[3]));
    mx = reduce_maxn<TPB>(mx, sA, tid);
    float Sm = 0.0f, Sx = 0.0f, Sy = 0.0f;
    for (int i = 0; i < 4; i++){
      const int px = tid + i*TPB;
      const float e = expf(kBeta * (fn[i] - mx));
      Sm += e; Sx += e * (float)(px>>6); Sy += e * (float)(px&63);
    }
    reduce3n<TPB>(Sm, Sx, Sy, sA, sB, sC, tid);
    if (tid == 0){
      float nrm = sqrtf(a0*a0 + a1*a1 + a2*a2);
      nrm = fmaxf(nrm, 1e-12f);
      out[O_CV + m*3 + 0] = a0/nrm;
      out[O_CV + m*3 + 1] = a1/nrm;
      out[O_CV + m*3 + 2] = a2/nrm;
      const float sxs = (float)ishape[1] / 64.0f;
      const float sys = (float)ishape[0] / 64.0f;
      out[O_CP + m*2 + 0] = Sx/Sm * sxs;
      out[O_CP + m*2 + 1] = Sy/Sm * sys;
    }
  } else {
    const int which = blk - 528;
    if (tid < 128){
      float s, c;
      sincosf(-6.283185307179586f * (float)tid / 128.0f, &s, &c);
      TW[tid] = {c, s};
    }
    for (int s = tid; s < 8192; s += TPB){
      const int y = s>>6, m = s&63;
      const cplx v0 = wval(y, 2*m, which);
      const cplx v1 = wval(y, 2*m+1, which);
      S4[PH(y, m)] = {v0.x, v0.y, v1.x, v1.y};
    }
    __syncthreads();
    row_s1_fwd<128,false>(S4, TW, tid);
    row_s2_fwd<128>(S4, tid);
    col_s1_fwd<false>(S4, TW, tid);
    col_s2_fwd_store(S4, (cplx*)((which==0)?W1:W2), tid);
  }
}

// ---------------- conv: blocks 0..255 conv1, 256..511 conv2 ----------------
__global__ __launch_bounds__(TPB,4) void conv_kernel(const float* __restrict__ heat,
                                                     const float* __restrict__ mean_hm,
                                                     const float* __restrict__ fields,
                                                     const float* __restrict__ sf,
                                                     const float* __restrict__ W1g,
                                                     const float* __restrict__ W2g,
                                                     float* __restrict__ out_fn,
                                                     float* __restrict__ fds){
  __shared__ float4 S4[8192];
  __shared__ cplx TW[128];
  const int tid = threadIdx.x;
  const int n = blockIdx.x;
  const bool is1 = (n < 256);
  const int m_img = is1 ? n : (n - 256);
  if (tid < 128){
    float s, c;
    sincosf(-6.283185307179586f * (float)tid / 128.0f, &s, &c);
    TW[tid] = {c, s};
  }
  const float* f = fields + (size_t)m_img * 3 * NPIX;
  if (is1){
    const int bv = n >> 4, l = n & 15;
    const int j1 = bv*NJ + c_P1[l], j0 = bv*NJ + c_P0[l];
    const float* h1 = heat + (size_t)j1 * NPIX;
    const float* h0 = heat + (size_t)j0 * NPIX;
    const float dm = mean_hm[j1] - mean_hm[j0];
    for (int s = tid; s < 2048; s += TPB){
      const int y = s>>5, m = s&31;
      const int i = (y<<6) + 2*m;
      const float2 a = *(const float2*)(h1 + i);
      const float2 b = *(const float2*)(h0 + i);
      S4[PH(y, m)] = {a.x - b.x - dm, 0.f, a.y - b.y - dm, 0.f};
    }
  } else {
    for (int s = tid; s < 2048; s += TPB){
      const int y = s>>5, m = s&31;
      const int i = (y<<6) + 2*m;
      const float2 a = *(const float2*)(f + NPIX + i);   // ch1 -> re
      const float2 b = *(const float2*)(f + i);          // ch0 -> im
      S4[PH(y, m)] = {a.x, b.x, a.y, b.y};
    }
  }
  __syncthreads();
  row_s1_fwd<64,true>(S4, TW, tid);
  row_s2_fwd<64>(S4, tid);
  col_s1_fwd<true>(S4, TW, tid);
  col_s2_fused(S4, (const cplx*)(is1 ? W1g : W2g), tid);
  col_s1_inv(S4, TW, tid);
  row_s2_inv(S4, tid);
  row_s1_inv(S4, TW, tid);
  if (is1){
    float* o = out_fn + (size_t)n * 3 * NPIX;
    for (int s = tid; s < 2048; s += TPB){
      const int y = s>>5, m = s&31;
      const int i = (y<<6) + 2*m;
      const float4 v = S4[PH(y, m)];
      const float2 f0 = *(const float2*)(f + i);
      const float2 f1 = *(const float2*)(f + NPIX + i);
      const float2 f2 = *(const float2*)(f + 2*NPIX + i);
      const float cA = fmaxf(0.f, (-v.y)*f0.x + v.x*f1.x);
      const float cB = fmaxf(0.f, (-v.w)*f0.y + v.z*f1.y);
      *(float2*)(o + i)          = {f0.x*cA, f0.y*cB};
      *(float2*)(o + NPIX + i)   = {f1.x*cA, f1.y*cB};
      *(float2*)(o + 2*NPIX + i) = {f2.x*cA, f2.y*cB};
    }
  } else {
    const float sc = sf[m_img];
    float* o = fds + (size_t)m_img * NPIX;
    for (int s = tid; s < 2048; s += TPB){
      const int y = s>>5, m = s&31;
      const int i = (y<<6) + 2*m;
      const float4 v = S4[PH(y, m)];
      *(float2*)(o + i) = {v.x*sc, v.z*sc};
    }
  }
}

// ---------------- hms_new + normalize + soft-argmax + kps combine ----------------
__global__ __launch_bounds__(HTPB) void hms_kernel(const float* __restrict__ heat,
                                                   const float* __restrict__ mean_hm,
                                                   const float* __restrict__ std_hm,
                                                   const float* __restrict__ fds,
                                                   const float* __restrict__ confs,
                                                   const int* __restrict__ ishape,
                                                   const float* __restrict__ pth1p,
                                                   const float* __restrict__ pth2p,
                                                   float* __restrict__ out){
  __shared__ float sA[HTPB], sB[HTPB], sC[HTPB];
  const int tid = threadIdx.x;
  const int idx = blockIdx.x;           // bv*17 + j
  const int bv = idx / NJ, j = idx % NJ;
  const float* hp = heat + (size_t)idx * NPIX;
  const float mh = mean_hm[idx];
  const int pl = c_proxL[j], dl = c_distL[j];
  const float* fp = (pl >= 0) ? fds + (size_t)(bv*NL + pl) * NPIX : nullptr;
  const float* fd = (dl >= 0) ? fds + (size_t)(bv*NL + dl) * NPIX : nullptr;
  float ho[16], hn[16];
  float s = 0.0f, s2 = 0.0f, dummy = 0.0f;
  for (int i = 0; i < 16; i++){
    const int px = tid + i*HTPB;
    const float h = hp[px] - mh;
    ho[i] = h;
    float m = h;
    if (pl >= 0) m *= fmaxf(0.0f, -fp[px]);
    if (dl >= 0) m *= fmaxf(0.0f, fd[px]);
    hn[i] = m;
    s += m; s2 += m*m;
  }
  reduce3n<HTPB>(s, s2, dummy, sA, sB, sC, tid);
  const float var = (s2 - s*s/4096.0f) / 4095.0f;
  const float sdn = sqrtf(fmaxf(var, 0.0f));
  const float scale = std_hm[idx] / (sdn + 1e-6f);
  float* ohm = out + O_HM + (size_t)idx * NPIX;
  for (int i = 0; i < 16; i++){
    hn[i] *= scale;
    ohm[tid + i*HTPB] = hn[i];
  }
  float mo = -1e30f, mn = -1e30f;
  for (int i = 0; i < 16; i++){ mo = fmaxf(mo, ho[i]); mn = fmaxf(mn, hn[i]); }
  mo = reduce_maxn<HTPB>(mo, sA, tid);
  mn = reduce_maxn<HTPB>(mn, sA, tid);
  float So = 0.0f, Sxo = 0.0f, Syo = 0.0f;
  float Sn = 0.0f, Sxn = 0.0f, Syn = 0.0f;
  for (int i = 0; i < 16; i++){
    const int px = tid + i*HTPB;
    const float y = (float)(px >> 6), x = (float)(px & 63);
    const float eo = expf(kBeta * (ho[i] - mo));
    So += eo; Sxo += eo*y; Syo += eo*x;
    const float en = expf(kBeta * (hn[i] - mn));
    Sn += en; Sxn += en*y; Syn += en*x;
  }
  reduce3n<HTPB>(So, Sxo, Syo, sA, sB, sC, tid);
  reduce3n<HTPB>(Sn, Sxn, Syn, sA, sB, sC, tid);
  if (tid == 0){
    const float sxs = (float)ishape[1] / 64.0f;
    const float sys = (float)ishape[0] / 64.0f;
    const float kxo = Sxo/So * sxs, kyo = Syo/So * sys;
    float kxn = Sxn/Sn * sxs, kyn = Syn/Sn * sys;
    if (kxn != kxn) kxn = kxo;
    if (kyn != kyn) kyn = kyo;
    const float ddx = kxn - kxo, ddy = kyn - kyo;
    const float disp = sqrtf(ddx*ddx + ddy*ddy);
    const float conf = confs[bv*(NL+NJ) + NL + j];
    const bool sel = (conf > pth1p[0]) && (disp < pth2p[0]);
    out[O_KPS + idx*2 + 0] = sel ? kxn : kxo;
    out[O_KPS + idx*2 + 1] = sel ? kyn : kyo;
  }
}

extern "C" void kernel_launch(void* const* d_in, const int* in_sizes, int n_in,
                              void* d_out, int out_size, void* d_ws, size_t ws_size,
                              hipStream_t stream) {
  const float* heat   = (const float*)d_in[0];
  const float* fields = (const float*)d_in[1];
  const int*   ishape = (const int*)d_in[5];
  const float* confs  = (const float*)d_in[6];
  const float* pth1   = (const float*)d_in[9];
  const float* pth2   = (const float*)d_in[10];
  float* out = (float*)d_out;
  float* ws = (float*)d_ws;
  float* fds     = ws + W_FDS;
  float* mean_hm = ws + W_MEAN;
  float* std_hm  = ws + W_STD;
  float* sf      = ws + W_SF;
  float* W1      = ws + W_W1;
  float* W2      = ws + W_W2;

  hipLaunchKernelGGL(pre_kernel, dim3(530), dim3(TPB), 0, stream,
                     heat, fields, ishape, mean_hm, std_hm, sf, W1, W2, out);
  hipLaunchKernelGGL(conv_kernel, dim3(512), dim3(TPB), 0, stream,
                     heat, mean_hm, fields, sf, W1, W2, out + O_FN, fds);
  hipLaunchKernelGGL(hms_kernel, dim3(272), dim3(HTPB), 0, stream,
                     heat, mean_hm, std_hm, fds, confs, ishape, pth1, pth2, out);
}

// Round 4
// 152.965 us; speedup vs baseline: 1.9561x; 1.0444x over previous
//
#include <hip/hip_runtime.h>
#include <math.h>

#define TPB 1024
#define HTPB 256
#define NPIX 4096
#define NJ 17
#define NL 16
static constexpr float kBeta = 100.0f;
static constexpr float S2H = 0.70710678118654752f;

// output layout (floats): kps(544) | comb_v(768) | comb_p(512) | fields_new(3145728) | hms_new(1114112)
#define O_KPS 0
#define O_CV 544
#define O_CP 1312
#define O_FN 1824
#define O_HM 3147552
// workspace layout (floats)
#define W_FDS 0               // 256*4096
#define W_MEAN 1048576        // 272
#define W_STD 1048848         // 272
#define W_SF 1049120          // 256
#define W_W1 1049376          // 16384 cplx
#define W_W2 1082144          // 16384 cplx

__device__ __constant__ int c_P0[16] = {0,1,2,0,4,5,0,7,8,9,8,11,12,8,14,15};
__device__ __constant__ int c_P1[16] = {1,2,3,4,5,6,7,8,9,10,11,12,13,14,15,16};
__device__ __constant__ int c_proxL[17] = {6,1,2,-1,4,5,-1,7,13,9,-1,11,12,-1,14,15,-1};
__device__ __constant__ int c_distL[17] = {-1,0,1,2,3,4,5,6,7,8,9,10,11,12,13,14,15};

using cplx = float2;
__device__ inline cplx cadd(cplx a, cplx b){ return {a.x+b.x, a.y+b.y}; }
__device__ inline cplx csub(cplx a, cplx b){ return {a.x-b.x, a.y-b.y}; }
__device__ inline cplx cmul(cplx a, cplx w){ return {a.x*w.x - a.y*w.y, a.x*w.y + a.y*w.x}; }
__device__ inline cplx cmulc(cplx a, cplx w){ return {a.x*w.x + a.y*w.y, a.y*w.x - a.x*w.y}; }

// w_128^{br3(p)} and w_16^{br3(p)}, br3 = {0,4,2,6,1,5,3,7}
__device__ __constant__ float2 W128BR[8] = {
  {1.f,0.f},
  {0.98078528040323044913f,-0.19509032201612826785f},
  {0.99518472667219688624f,-0.09801714032956060199f},
  {0.95694033573220886494f,-0.29028467725446236764f},
  {0.99879545620517239271f,-0.04906767432741801425f},
  {0.97003125319454399260f,-0.24298017990326388995f},
  {0.98917650996478097345f,-0.14673047445536175166f},
  {0.94154406518302077841f,-0.33688985339222005069f}
};
__device__ __constant__ float2 W16BR[8] = {
  {1.f,0.f},
  {0.f,-1.f},
  {0.70710678118654752440f,-0.70710678118654752440f},
  {-0.70710678118654752440f,-0.70710678118654752440f},
  {0.92387953251128675613f,-0.38268343236508977173f},
  {-0.38268343236508977173f,-0.92387953251128675613f},
  {0.38268343236508977173f,-0.92387953251128675613f},
  {-0.92387953251128675613f,-0.38268343236508977173f}
};

// -------- 8-point DFT (radix-2 DIF, output bit-reversed); inverse = exact inverse (gain 8) ----
__device__ inline void bf8_tail(cplx t0, cplx t1, cplx t2, cplx t3,
                                cplx t4, cplx t5, cplx t6, cplx t7, cplx x[8]){
  cplx u0=cadd(t0,t2), u2=csub(t0,t2);
  cplx u1=cadd(t1,t3), d13=csub(t1,t3);
  cplx u3={d13.y,-d13.x};
  cplx u4=cadd(t4,t6), u6=csub(t4,t6);
  cplx u5=cadd(t5,t7), d57=csub(t5,t7);
  cplx u7={d57.y,-d57.x};
  x[0]=cadd(u0,u1); x[1]=csub(u0,u1);
  x[2]=cadd(u2,u3); x[3]=csub(u2,u3);
  x[4]=cadd(u4,u5); x[5]=csub(u4,u5);
  x[6]=cadd(u6,u7); x[7]=csub(u6,u7);
}
__device__ inline void bf8_fwd(cplx x[8]){
  cplx t0=cadd(x[0],x[4]), d4=csub(x[0],x[4]);
  cplx t1=cadd(x[1],x[5]), d5=csub(x[1],x[5]);
  cplx t2=cadd(x[2],x[6]), d6=csub(x[2],x[6]);
  cplx t3=cadd(x[3],x[7]), d7=csub(x[3],x[7]);
  cplx t5={S2H*(d5.x+d5.y), S2H*(d5.y-d5.x)};
  cplx t6={d6.y,-d6.x};
  cplx t7={S2H*(d7.y-d7.x), -S2H*(d7.x+d7.y)};
  bf8_tail(t0,t1,t2,t3,d4,t5,t6,t7,x);
}
__device__ inline void bf8_fwd_z(cplx x[8]){   // x[4..7] == 0 implicitly
  cplx t5={S2H*(x[1].x+x[1].y), S2H*(x[1].y-x[1].x)};
  cplx t6={x[2].y,-x[2].x};
  cplx t7={S2H*(x[3].y-x[3].x), -S2H*(x[3].x+x[3].y)};
  bf8_tail(x[0],x[1],x[2],x[3],x[0],t5,t6,t7,x);
}
__device__ inline void bf8_inv(cplx y[8]){
  cplx u0=cadd(y[0],y[1]), u1=csub(y[0],y[1]);
  cplx u2=cadd(y[2],y[3]), u3=csub(y[2],y[3]);
  cplx u4=cadd(y[4],y[5]), u5=csub(y[4],y[5]);
  cplx u6=cadd(y[6],y[7]), u7=csub(y[6],y[7]);
  cplx t0=cadd(u0,u2), t2=csub(u0,u2);
  cplx iu3={-u3.y,u3.x};
  cplx t1=cadd(u1,iu3), t3=csub(u1,iu3);
  cplx t4=cadd(u4,u6), t6=csub(u4,u6);
  cplx iu7={-u7.y,u7.x};
  cplx t5=cadd(u5,iu7), t7=csub(u5,iu7);
  y[0]=cadd(t0,t4); y[4]=csub(t0,t4);
  cplx w5={S2H*(t5.x-t5.y), S2H*(t5.x+t5.y)};
  y[1]=cadd(t1,w5); y[5]=csub(t1,w5);
  cplx w6={-t6.y,t6.x};
  y[2]=cadd(t2,w6); y[6]=csub(t2,w6);
  cplx w7={-S2H*(t7.x+t7.y), S2H*(t7.x-t7.y)};
  y[3]=cadd(t3,w7); y[7]=csub(t3,w7);
}

// -------- 16-point DFT in registers (8x2); inverse = exact inverse (gain 16) ----------------
__device__ inline void fft16_fwd(cplx z[16]){
  cplx e[8], o[8];
  #pragma unroll
  for (int t=0;t<8;t++){ e[t]=z[2*t]; o[t]=z[2*t+1]; }
  bf8_fwd(e); bf8_fwd(o);
  #pragma unroll
  for (int p=0;p<8;p++){
    cplx vo = cmul(o[p], W16BR[p]);
    z[2*p]   = cadd(e[p], vo);
    z[2*p+1] = csub(e[p], vo);
  }
}
__device__ inline void fft16_inv(cplx z[16]){
  cplx e[8], o[8];
  #pragma unroll
  for (int p=0;p<8;p++){
    cplx a=z[2*p], b=z[2*p+1];
    e[p] = cadd(a,b);
    o[p] = cmulc(csub(a,b), W16BR[p]);
  }
  bf8_inv(e); bf8_inv(o);
  #pragma unroll
  for (int t=0;t<8;t++){ z[2*t]=e[t]; z[2*t+1]=o[t]; }
}

// A[p] = w_128^{j*br3(p)} via chain from TW[j]
__device__ inline void twchainA(const cplx* TW, int j, cplx A[8]){
  cplx W1 = TW[j];
  cplx W2 = cmul(W1,W1);
  cplx W4 = cmul(W2,W2);
  cplx W6 = cmul(W4,W2);
  A[0] = {1.f,0.f}; A[1] = W4; A[2] = W2; A[3] = W6;
  A[4] = W1; A[5] = cmul(W4,W1); A[6] = cmul(W2,W1); A[7] = cmul(W6,W1);
}

// physical f4-slot for logical (row y, slot-in-row m):
__device__ inline int PH(int y, int m){ return (y<<6) | ((m ^ ((y&7)*9)) & 63); }

// ---------------- passes (S4 = float4[8192], 128x64 slots) --------------------------------
// 128-line variants (prep path; 1024 threads naturally)
template<int NLINES, bool ZT>
__device__ void row_s1_fwd(float4* S4, const cplx* TW, int tid){
  if (tid < NLINES*8){
    const int L = tid>>3, m = tid&7;
    cplx xe[8], xo[8];
    #pragma unroll
    for (int t=0; t<(ZT?4:8); t++){
      float4 v = S4[PH(L, m+8*t)];
      xe[t]={v.x,v.y}; xo[t]={v.z,v.w};
    }
    if (ZT){ bf8_fwd_z(xe); bf8_fwd_z(xo); } else { bf8_fwd(xe); bf8_fwd(xo); }
    cplx A[8]; twchainA(TW, 2*m, A);
    #pragma unroll
    for (int p=0;p<8;p++){
      cplx B = cmul(A[p], W128BR[p]);
      cplx ve = cmul(xe[p], A[p]);
      cplx vo = cmul(xo[p], B);
      S4[PH(L, m+8*p)] = {ve.x, ve.y, vo.x, vo.y};
    }
  }
  __syncthreads();
}
// 64-line all-thread (1024) variants: lane pairs split the two f4 channels
__device__ void row_s1_fwd64a(float4* S4, const cplx* TW, int tid){   // ZT
  float2* Sc = (float2*)S4;
  const int u = tid >> 1, ch = tid & 1;
  const int L = u >> 3, m = u & 7;
  cplx x[8];
  #pragma unroll
  for (int t=0;t<4;t++) x[t] = Sc[2*PH(L, m+8*t) + ch];
  bf8_fwd_z(x);
  cplx A[8]; twchainA(TW, 2*m, A);
  #pragma unroll
  for (int p=0;p<8;p++){
    const cplx w = ch ? cmul(A[p], W128BR[p]) : A[p];
    Sc[2*PH(L, m+8*p) + ch] = cmul(x[p], w);
  }
  __syncthreads();
}
__device__ void row_s1_inv64a(float4* S4, const cplx* TW, int tid){
  float2* Sc = (float2*)S4;
  const int u = tid >> 1, ch = tid & 1;
  const int L = u >> 3, m = u & 7;
  cplx x[8];
  #pragma unroll
  for (int p=0;p<8;p++) x[p] = Sc[2*PH(L, m+8*p) + ch];
  cplx A[8]; twchainA(TW, 2*m, A);
  #pragma unroll
  for (int p=0;p<8;p++){
    const cplx w = ch ? cmul(A[p], W128BR[p]) : A[p];
    x[p] = cmulc(x[p], w);
  }
  bf8_inv(x);
  #pragma unroll
  for (int t=0;t<4;t++) Sc[2*PH(L, m+8*t) + ch] = x[t];
  __syncthreads();
}
template<int NLINES>
__device__ void row_s2_fwd(float4* S4, int tid){
  if (tid < NLINES*8){
    const int L = tid>>3, jb = tid&7;
    cplx z[16];
    #pragma unroll
    for (int k=0;k<8;k++){
      float4 v = S4[PH(L, jb*8+k)];
      z[2*k]={v.x,v.y}; z[2*k+1]={v.z,v.w};
    }
    fft16_fwd(z);
    #pragma unroll
    for (int k=0;k<8;k++)
      S4[PH(L, jb*8+k)] = {z[2*k].x, z[2*k].y, z[2*k+1].x, z[2*k+1].y};
  }
  __syncthreads();
}
__device__ void row_s2_inv(float4* S4, int tid){   // 64 lines
  if (tid < 512){
    const int L = tid>>3, jb = tid&7;
    cplx z[16];
    #pragma unroll
    for (int k=0;k<8;k++){
      float4 v = S4[PH(L, jb*8+k)];
      z[2*k]={v.x,v.y}; z[2*k+1]={v.z,v.w};
    }
    fft16_inv(z);
    #pragma unroll
    for (int k=0;k<8;k++)
      S4[PH(L, jb*8+k)] = {z[2*k].x, z[2*k].y, z[2*k+1].x, z[2*k+1].y};
  }
  __syncthreads();
}
template<bool ZT>
__device__ void col_s1_fwd(float4* S4, const cplx* TW, int tid){
  const int cp = tid & 63, yj = tid >> 6;           // 1024 units
  const int sl = (cp ^ ((yj&7)*9)) & 63;
  cplx xe[8], xo[8];
  #pragma unroll
  for (int t=0; t<(ZT?4:8); t++){
    float4 v = S4[((yj+16*t)<<6) | sl];
    xe[t]={v.x,v.y}; xo[t]={v.z,v.w};
  }
  if (ZT){ bf8_fwd_z(xe); bf8_fwd_z(xo); } else { bf8_fwd(xe); bf8_fwd(xo); }
  cplx A[8]; twchainA(TW, yj, A);
  #pragma unroll
  for (int p=0;p<8;p++){
    cplx ve = cmul(xe[p], A[p]);
    cplx vo = cmul(xo[p], A[p]);
    S4[((yj+16*p)<<6) | sl] = {ve.x, ve.y, vo.x, vo.y};
  }
  __syncthreads();
}
__device__ void col_s1_inv(float4* S4, const cplx* TW, int tid){   // write t<4 (rows y<64)
  const int cp = tid & 63, yj = tid >> 6;
  const int sl = (cp ^ ((yj&7)*9)) & 63;
  cplx xe[8], xo[8];
  #pragma unroll
  for (int p=0;p<8;p++){
    float4 v = S4[((yj+16*p)<<6) | sl];
    xe[p]={v.x,v.y}; xo[p]={v.z,v.w};
  }
  cplx A[8]; twchainA(TW, yj, A);
  #pragma unroll
  for (int p=0;p<8;p++){
    xe[p] = cmulc(xe[p], A[p]);
    xo[p] = cmulc(xo[p], A[p]);
  }
  bf8_inv(xe); bf8_inv(xo);
  #pragma unroll
  for (int t=0;t<4;t++)
    S4[((yj+16*t)<<6) | sl] = {xe[t].x, xe[t].y, xo[t].x, xo[t].y};
  __syncthreads();
}
// fused: col s2 forward -> pointwise * Wg -> col s2 inverse, all in registers (W prefetched)
__device__ void col_s2_fused(float4* S4, const cplx* __restrict__ Wg, int tid){
  cplx* Sc = (cplx*)S4;
  const int c = tid & 127, r = tid >> 7;
  const int ch = c & 1, cp = c >> 1;
  int ad[16];
  cplx z[16], wv[16];
  #pragma unroll
  for (int i=0;i<16;i++) wv[i] = Wg[(16*r+i)*128 + c];   // L2 loads in flight during FFT
  #pragma unroll
  for (int i=0;i<16;i++){
    const int y = 16*r + i;
    ad[i] = ((((y<<6) | ((cp ^ ((y&7)*9)) & 63)) << 1) | ch);
    z[i] = Sc[ad[i]];
  }
  fft16_fwd(z);
  #pragma unroll
  for (int i=0;i<16;i++) z[i] = cmul(z[i], wv[i]);
  fft16_inv(z);
  #pragma unroll
  for (int i=0;i<16;i++) Sc[ad[i]] = z[i];
  __syncthreads();
}
// prep: col s2 forward, store spectrum directly to global (scaled)
__device__ void col_s2_fwd_store(float4* S4, cplx* __restrict__ Wo, int tid){
  cplx* Sc = (cplx*)S4;
  const int c = tid & 127, r = tid >> 7;
  const int ch = c & 1, cp = c >> 1;
  cplx z[16];
  #pragma unroll
  for (int i=0;i<16;i++){
    const int y = 16*r + i;
    z[i] = Sc[(((y<<6) | ((cp ^ ((y&7)*9)) & 63)) << 1) | ch];
  }
  fft16_fwd(z);
  const float scl = 1.0f / 16384.0f;
  #pragma unroll
  for (int i=0;i<16;i++) Wo[(16*r+i)*128 + c] = {z[i].x*scl, z[i].y*scl};
}

// ---------------- wave-shuffle block reductions ----------------
__device__ inline float wred(float v){
  #pragma unroll
  for (int o=32;o;o>>=1) v += __shfl_xor(v, o, 64);
  return v;
}
__device__ inline float wredmax(float v){
  #pragma unroll
  for (int o=32;o;o>>=1) v = fmaxf(v, __shfl_xor(v, o, 64));
  return v;
}
template<int NW>
__device__ inline void bred3(float& a, float& b, float& c,
                             float* s0, float* s1, float* s2, int tid){
  a = wred(a); b = wred(b); c = wred(c);
  const int w = tid >> 6;
  if ((tid & 63) == 0){ s0[w]=a; s1[w]=b; s2[w]=c; }
  __syncthreads();
  if (tid == 0){
    float A=0.f, B=0.f, C=0.f;
    #pragma unroll
    for (int i=0;i<NW;i++){ A+=s0[i]; B+=s1[i]; C+=s2[i]; }
    s0[0]=A; s1[0]=B; s2[0]=C;
  }
  __syncthreads();
  a = s0[0]; b = s1[0]; c = s2[0];
  __syncthreads();
}
template<int NW>
__device__ inline float bredmax(float v, float* s0, int tid){
  v = wredmax(v);
  const int w = tid >> 6;
  if ((tid & 63) == 0) s0[w] = v;
  __syncthreads();
  if (tid == 0){
    float M = s0[0];
    #pragma unroll
    for (int i=1;i<NW;i++) M = fmaxf(M, s0[i]);
    s0[0] = M;
  }
  __syncthreads();
  const float r = s0[0];
  __syncthreads();
  return r;
}

__device__ inline cplx wval(int r, int c, int which){
  const int dy = (r<64)? r : r-128;
  const int dx = (c<64)? c : c-128;
  float a, b;
  if (which==0){ a = 1.f-(float)dy; b = 1.f-(float)dx; }
  else         { a = 1.f+(float)dy; b = 1.f+(float)dx; }
  const float den = a*a + b*b;
  if (r==64 || c==64 || den<=0.f) return {0.f,0.f};
  const float inv = 1.f/den;
  return {a*inv, -b*inv};
}

// ---------------- pre: blk 0,1 = kernel-FFT prep (runs FIRST, overlaps stats) -------------
__global__ __launch_bounds__(TPB,4) void pre_kernel(const float* __restrict__ heat,
                                                    const float* __restrict__ fields,
                                                    const int* __restrict__ ishape,
                                                    float* __restrict__ mean_hm,
                                                    float* __restrict__ std_hm,
                                                    float* __restrict__ sf,
                                                    float* __restrict__ W1,
                                                    float* __restrict__ W2,
                                                    float* __restrict__ out){
  __shared__ float4 S4[8192];
  __shared__ cplx TW[128];
  __shared__ float sA[16], sB[16], sC[16];
  const int tid = threadIdx.x;
  const int blk = blockIdx.x;
  if (blk < 2){
    const int which = blk;
    if (tid < 128){
      float s, c;
      sincosf(-6.283185307179586f * (float)tid / 128.0f, &s, &c);
      TW[tid] = {c, s};
    }
    for (int s = tid; s < 8192; s += TPB){
      const int y = s>>6, m = s&63;
      const cplx v0 = wval(y, 2*m, which);
      const cplx v1 = wval(y, 2*m+1, which);
      S4[PH(y, m)] = {v0.x, v0.y, v1.x, v1.y};
    }
    __syncthreads();
    row_s1_fwd<128,false>(S4, TW, tid);
    row_s2_fwd<128>(S4, tid);
    col_s1_fwd<false>(S4, TW, tid);
    col_s2_fwd_store(S4, (cplx*)((which==0)?W1:W2), tid);
  } else if (blk < 274){
    const int n = blk - 2;
    const float* p = heat + (size_t)n * NPIX;
    float s = 0.0f, s2 = 0.0f, d = 0.0f;
    #pragma unroll
    for (int i = 0; i < 4; i++){
      const float x = p[tid + i*TPB];
      s += x; s2 += x*x;
    }
    bred3<16>(s, s2, d, sA, sB, sC, tid);
    if (tid == 0){
      const float mean = s / 4096.0f;
      const float var = (s2 - s*mean) / 4095.0f;
      mean_hm[n] = mean;
      std_hm[n] = sqrtf(fmaxf(var, 0.0f));
    }
  } else {
    const int m = blk - 274;
    const float* f = fields + (size_t)m * 3 * NPIX;
    float s1 = 0.0f, s2 = 0.0f;
    float a0 = 0.0f, a1 = 0.0f, a2 = 0.0f;
    float fn[4];
    #pragma unroll
    for (int i = 0; i < 4; i++){
      const int px = tid + i*TPB;
      const float f0 = f[px], f1 = f[NPIX+px], f2 = f[2*NPIX+px];
      s1 += f0+f1+f2; s2 += f0*f0+f1*f1+f2*f2;
      const float nn = sqrtf(f0*f0 + f1*f1 + f2*f2);
      fn[i] = nn;
      a0 += nn*f0; a1 += nn*f1; a2 += nn*f2;
    }
    {
      float t1 = s1, t2 = s2, t3 = 0.0f;
      bred3<16>(t1, t2, t3, sA, sB, sC, tid);
      if (tid == 0){
        const float var = (t2 - t1*t1/12288.0f) / 12287.0f;
        const float sd = sqrtf(fmaxf(var, 0.0f));
        sf[m] = sd / (sd + 1e-6f);
      }
    }
    bred3<16>(a0, a1, a2, sA, sB, sC, tid);
    float mx = fmaxf(fmaxf(fn[0],fn[1]), fmaxf(fn[2],fn[3]));
    mx = bredmax<16>(mx, sA, tid);
    float Sm = 0.0f, Sx = 0.0f, Sy = 0.0f;
    #pragma unroll
    for (int i = 0; i < 4; i++){
      const int px = tid + i*TPB;
      const float e = expf(kBeta * (fn[i] - mx));
      Sm += e; Sx += e * (float)(px>>6); Sy += e * (float)(px&63);
    }
    bred3<16>(Sm, Sx, Sy, sA, sB, sC, tid);
    if (tid == 0){
      float nrm = sqrtf(a0*a0 + a1*a1 + a2*a2);
      nrm = fmaxf(nrm, 1e-12f);
      out[O_CV + m*3 + 0] = a0/nrm;
      out[O_CV + m*3 + 1] = a1/nrm;
      out[O_CV + m*3 + 2] = a2/nrm;
      const float sxs = (float)ishape[1] / 64.0f;
      const float sys = (float)ishape[0] / 64.0f;
      out[O_CP + m*2 + 0] = Sx/Sm * sxs;
      out[O_CP + m*2 + 1] = Sy/Sm * sys;
    }
  }
}

// ---------------- conv: blocks 0..255 conv2 (fds first), 256..511 conv1 ----------------
__global__ __launch_bounds__(TPB,4) void conv_kernel(const float* __restrict__ heat,
                                                     const float* __restrict__ mean_hm,
                                                     const float* __restrict__ fields,
                                                     const float* __restrict__ sf,
                                                     const float* __restrict__ W1g,
                                                     const float* __restrict__ W2g,
                                                     float* __restrict__ out_fn,
                                                     float* __restrict__ fds){
  __shared__ float4 S4[8192];
  __shared__ cplx TW[128];
  const int tid = threadIdx.x;
  const int n = blockIdx.x;
  const bool is2 = (n < 256);
  const int m_img = is2 ? n : (n - 256);
  if (tid < 128){
    float s, c;
    sincosf(-6.283185307179586f * (float)tid / 128.0f, &s, &c);
    TW[tid] = {c, s};
  }
  const float* f = fields + (size_t)m_img * 3 * NPIX;
  if (!is2){
    const int bv = m_img >> 4, l = m_img & 15;
    const int j1 = bv*NJ + c_P1[l], j0 = bv*NJ + c_P0[l];
    const float* h1 = heat + (size_t)j1 * NPIX;
    const float* h0 = heat + (size_t)j0 * NPIX;
    const float dm = mean_hm[j1] - mean_hm[j0];
    for (int s = tid; s < 2048; s += TPB){
      const int y = s>>5, m = s&31;
      const int i = (y<<6) + 2*m;
      const float2 a = *(const float2*)(h1 + i);
      const float2 b = *(const float2*)(h0 + i);
      S4[PH(y, m)] = {a.x - b.x - dm, 0.f, a.y - b.y - dm, 0.f};
    }
  } else {
    for (int s = tid; s < 2048; s += TPB){
      const int y = s>>5, m = s&31;
      const int i = (y<<6) + 2*m;
      const float2 a = *(const float2*)(f + NPIX + i);   // ch1 -> re
      const float2 b = *(const float2*)(f + i);          // ch0 -> im
      S4[PH(y, m)] = {a.x, b.x, a.y, b.y};
    }
  }
  __syncthreads();
  row_s1_fwd64a(S4, TW, tid);
  row_s2_fwd<64>(S4, tid);
  col_s1_fwd<true>(S4, TW, tid);
  col_s2_fused(S4, (const cplx*)(is2 ? W2g : W1g), tid);
  col_s1_inv(S4, TW, tid);
  row_s2_inv(S4, tid);
  row_s1_inv64a(S4, TW, tid);
  if (!is2){
    float* o = out_fn + (size_t)m_img * 3 * NPIX;
    for (int s = tid; s < 2048; s += TPB){
      const int y = s>>5, m = s&31;
      const int i = (y<<6) + 2*m;
      const float4 v = S4[PH(y, m)];
      const float2 f0 = *(const float2*)(f + i);
      const float2 f1 = *(const float2*)(f + NPIX + i);
      const float2 f2 = *(const float2*)(f + 2*NPIX + i);
      const float cA = fmaxf(0.f, (-v.y)*f0.x + v.x*f1.x);
      const float cB = fmaxf(0.f, (-v.w)*f0.y + v.z*f1.y);
      *(float2*)(o + i)          = {f0.x*cA, f0.y*cB};
      *(float2*)(o + NPIX + i)   = {f1.x*cA, f1.y*cB};
      *(float2*)(o + 2*NPIX + i) = {f2.x*cA, f2.y*cB};
    }
  } else {
    const float sc = sf[m_img];
    float* o = fds + (size_t)m_img * NPIX;
    for (int s = tid; s < 2048; s += TPB){
      const int y = s>>5, m = s&31;
      const int i = (y<<6) + 2*m;
      const float4 v = S4[PH(y, m)];
      *(float2*)(o + i) = {v.x*sc, v.z*sc};
    }
  }
}

// ---------------- hms_new + normalize + soft-argmax + kps combine ----------------
__global__ __launch_bounds__(HTPB) void hms_kernel(const float* __restrict__ heat,
                                                   const float* __restrict__ mean_hm,
                                                   const float* __restrict__ std_hm,
                                                   const float* __restrict__ fds,
                                                   const float* __restrict__ confs,
                                                   const int* __restrict__ ishape,
                                                   const float* __restrict__ pth1p,
                                                   const float* __restrict__ pth2p,
                                                   float* __restrict__ out){
  __shared__ float sA[4], sB[4], sC[4];
  const int tid = threadIdx.x;
  const int idx = blockIdx.x;           // bv*17 + j
  const int bv = idx / NJ, j = idx % NJ;
  const float* hp = heat + (size_t)idx * NPIX;
  const float mh = mean_hm[idx];
  const int pl = c_proxL[j], dl = c_distL[j];
  const float* fp = (pl >= 0) ? fds + (size_t)(bv*NL + pl) * NPIX : nullptr;
  const float* fd = (dl >= 0) ? fds + (size_t)(bv*NL + dl) * NPIX : nullptr;
  float ho[16], hn[16];
  float s = 0.0f, s2 = 0.0f, dummy = 0.0f;
  #pragma unroll
  for (int i = 0; i < 16; i++){
    const int px = tid + i*HTPB;
    const float h = hp[px] - mh;
    ho[i] = h;
    float m = h;
    if (pl >= 0) m *= fmaxf(0.0f, -fp[px]);
    if (dl >= 0) m *= fmaxf(0.0f, fd[px]);
    hn[i] = m;
    s += m; s2 += m*m;
  }
  bred3<4>(s, s2, dummy, sA, sB, sC, tid);
  const float var = (s2 - s*s/4096.0f) / 4095.0f;
  const float sdn = sqrtf(fmaxf(var, 0.0f));
  const float scale = std_hm[idx] / (sdn + 1e-6f);
  float* ohm = out + O_HM + (size_t)idx * NPIX;
  #pragma unroll
  for (int i = 0; i < 16; i++){
    hn[i] *= scale;
    ohm[tid + i*HTPB] = hn[i];
  }
  float mo = -1e30f, mn = -1e30f;
  #pragma unroll
  for (int i = 0; i < 16; i++){ mo = fmaxf(mo, ho[i]); mn = fmaxf(mn, hn[i]); }
  mo = bredmax<4>(mo, sA, tid);
  mn = bredmax<4>(mn, sA, tid);
  float So = 0.0f, Sxo = 0.0f, Syo = 0.0f;
  float Sn = 0.0f, Sxn = 0.0f, Syn = 0.0f;
  #pragma unroll
  for (int i = 0; i < 16; i++){
    const int px = tid + i*HTPB;
    const float y = (float)(px >> 6), x = (float)(px & 63);
    const float eo = expf(kBeta * (ho[i] - mo));
    So += eo; Sxo += eo*y; Syo += eo*x;
    const float en = expf(kBeta * (hn[i] - mn));
    Sn += en; Sxn += en*y; Syn += en*x;
  }
  bred3<4>(So, Sxo, Syo, sA, sB, sC, tid);
  bred3<4>(Sn, Sxn, Syn, sA, sB, sC, tid);
  if (tid == 0){
    const float sxs = (float)ishape[1] / 64.0f;
    const float sys = (float)ishape[0] / 64.0f;
    const float kxo = Sxo/So * sxs, kyo = Syo/So * sys;
    float kxn = Sxn/Sn * sxs, kyn = Syn/Sn * sys;
    if (kxn != kxn) kxn = kxo;
    if (kyn != kyn) kyn = kyo;
    const float ddx = kxn - kxo, ddy = kyn - kyo;
    const float disp = sqrtf(ddx*ddx + ddy*ddy);
    const float conf = confs[bv*(NL+NJ) + NL + j];
    const bool sel = (conf > pth1p[0]) && (disp < pth2p[0]);
    out[O_KPS + idx*2 + 0] = sel ? kxn : kxo;
    out[O_KPS + idx*2 + 1] = sel ? kyn : kyo;
  }
}

extern "C" void kernel_launch(void* const* d_in, const int* in_sizes, int n_in,
                              void* d_out, int out_size, void* d_ws, size_t ws_size,
                              hipStream_t stream) {
  const float* heat   = (const float*)d_in[0];
  const float* fields = (const float*)d_in[1];
  const int*   ishape = (const int*)d_in[5];
  const float* confs  = (const float*)d_in[6];
  const float* pth1   = (const float*)d_in[9];
  const float* pth2   = (const float*)d_in[10];
  float* out = (float*)d_out;
  float* ws = (float*)d_ws;
  float* fds     = ws + W_FDS;
  float* mean_hm = ws + W_MEAN;
  float* std_hm  = ws + W_STD;
  float* sf      = ws + W_SF;
  float* W1      = ws + W_W1;
  float* W2      = ws + W_W2;

  hipLaunchKernelGGL(pre_kernel, dim3(530), dim3(TPB), 0, stream,
                     heat, fields, ishape, mean_hm, std_hm, sf, W1, W2, out);
  hipLaunchKernelGGL(conv_kernel, dim3(512), dim3(TPB), 0, stream,
                     heat, mean_hm, fields, sf, W1, W2, out + O_FN, fds);
  hipLaunchKernelGGL(hms_kernel, dim3(272), dim3(HTPB), 0, stream,
                     heat, mean_hm, std_hm, fds, confs, ishape, pth1, pth2, out);
}

// Round 5
// 142.839 us; speedup vs baseline: 2.0947x; 1.0709x over previous
//
#include <hip/hip_runtime.h>
#include <math.h>

#define TPB 1024
#define HTPB 256
#define NPIX 4096
#define NJ 17
#define NL 16
static constexpr float kBeta = 100.0f;
static constexpr float S2H = 0.70710678118654752f;

// output layout (floats): kps(544) | comb_v(768) | comb_p(512) | fields_new(3145728) | hms_new(1114112)
#define O_KPS 0
#define O_CV 544
#define O_CP 1312
#define O_FN 1824
#define O_HM 3147552
// workspace layout (floats)
#define W_FDS 0               // 256*4096
#define W_MEAN 1048576        // 272
#define W_STD 1048848         // 272
#define W_SF 1049120          // 256
#define W_W1 1049376          // 16384 cplx
#define W_W2 1082144          // 16384 cplx

__device__ __constant__ int c_P0[16] = {0,1,2,0,4,5,0,7,8,9,8,11,12,8,14,15};
__device__ __constant__ int c_P1[16] = {1,2,3,4,5,6,7,8,9,10,11,12,13,14,15,16};
__device__ __constant__ int c_proxL[17] = {6,1,2,-1,4,5,-1,7,13,9,-1,11,12,-1,14,15,-1};
__device__ __constant__ int c_distL[17] = {-1,0,1,2,3,4,5,6,7,8,9,10,11,12,13,14,15};

using cplx = float2;
__device__ inline cplx cadd(cplx a, cplx b){ return {a.x+b.x, a.y+b.y}; }
__device__ inline cplx csub(cplx a, cplx b){ return {a.x-b.x, a.y-b.y}; }
__device__ inline cplx cmul(cplx a, cplx w){ return {a.x*w.x - a.y*w.y, a.x*w.y + a.y*w.x}; }
__device__ inline cplx cmulc(cplx a, cplx w){ return {a.x*w.x + a.y*w.y, a.y*w.x - a.x*w.y}; }

// intra-wave LDS sync: wave is lockstep; lgkmcnt(0) drains this wave's own ds ops.
__device__ inline void wsync(){
  asm volatile("s_waitcnt lgkmcnt(0)" ::: "memory");
}

// w_128^{br3(p)} and w_16^{br3(p)}, br3 = {0,4,2,6,1,5,3,7}
__device__ __constant__ float2 W128BR[8] = {
  {1.f,0.f},
  {0.98078528040323044913f,-0.19509032201612826785f},
  {0.99518472667219688624f,-0.09801714032956060199f},
  {0.95694033573220886494f,-0.29028467725446236764f},
  {0.99879545620517239271f,-0.04906767432741801425f},
  {0.97003125319454399260f,-0.24298017990326388995f},
  {0.98917650996478097345f,-0.14673047445536175166f},
  {0.94154406518302077841f,-0.33688985339222005069f}
};
__device__ __constant__ float2 W16BR[8] = {
  {1.f,0.f},
  {0.f,-1.f},
  {0.70710678118654752440f,-0.70710678118654752440f},
  {-0.70710678118654752440f,-0.70710678118654752440f},
  {0.92387953251128675613f,-0.38268343236508977173f},
  {-0.38268343236508977173f,-0.92387953251128675613f},
  {0.38268343236508977173f,-0.92387953251128675613f},
  {-0.92387953251128675613f,-0.38268343236508977173f}
};

// -------- 8-point DFT (radix-2 DIF, output bit-reversed); inverse = exact inverse (gain 8) ----
__device__ inline void bf8_tail(cplx t0, cplx t1, cplx t2, cplx t3,
                                cplx t4, cplx t5, cplx t6, cplx t7, cplx x[8]){
  cplx u0=cadd(t0,t2), u2=csub(t0,t2);
  cplx u1=cadd(t1,t3), d13=csub(t1,t3);
  cplx u3={d13.y,-d13.x};
  cplx u4=cadd(t4,t6), u6=csub(t4,t6);
  cplx u5=cadd(t5,t7), d57=csub(t5,t7);
  cplx u7={d57.y,-d57.x};
  x[0]=cadd(u0,u1); x[1]=csub(u0,u1);
  x[2]=cadd(u2,u3); x[3]=csub(u2,u3);
  x[4]=cadd(u4,u5); x[5]=csub(u4,u5);
  x[6]=cadd(u6,u7); x[7]=csub(u6,u7);
}
__device__ inline void bf8_fwd(cplx x[8]){
  cplx t0=cadd(x[0],x[4]), d4=csub(x[0],x[4]);
  cplx t1=cadd(x[1],x[5]), d5=csub(x[1],x[5]);
  cplx t2=cadd(x[2],x[6]), d6=csub(x[2],x[6]);
  cplx t3=cadd(x[3],x[7]), d7=csub(x[3],x[7]);
  cplx t5={S2H*(d5.x+d5.y), S2H*(d5.y-d5.x)};
  cplx t6={d6.y,-d6.x};
  cplx t7={S2H*(d7.y-d7.x), -S2H*(d7.x+d7.y)};
  bf8_tail(t0,t1,t2,t3,d4,t5,t6,t7,x);
}
__device__ inline void bf8_fwd_z(cplx x[8]){   // x[4..7] == 0 implicitly
  cplx t5={S2H*(x[1].x+x[1].y), S2H*(x[1].y-x[1].x)};
  cplx t6={x[2].y,-x[2].x};
  cplx t7={S2H*(x[3].y-x[3].x), -S2H*(x[3].x+x[3].y)};
  bf8_tail(x[0],x[1],x[2],x[3],x[0],t5,t6,t7,x);
}
__device__ inline void bf8_inv(cplx y[8]){
  cplx u0=cadd(y[0],y[1]), u1=csub(y[0],y[1]);
  cplx u2=cadd(y[2],y[3]), u3=csub(y[2],y[3]);
  cplx u4=cadd(y[4],y[5]), u5=csub(y[4],y[5]);
  cplx u6=cadd(y[6],y[7]), u7=csub(y[6],y[7]);
  cplx t0=cadd(u0,u2), t2=csub(u0,u2);
  cplx iu3={-u3.y,u3.x};
  cplx t1=cadd(u1,iu3), t3=csub(u1,iu3);
  cplx t4=cadd(u4,u6), t6=csub(u4,u6);
  cplx iu7={-u7.y,u7.x};
  cplx t5=cadd(u5,iu7), t7=csub(u5,iu7);
  y[0]=cadd(t0,t4); y[4]=csub(t0,t4);
  cplx w5={S2H*(t5.x-t5.y), S2H*(t5.x+t5.y)};
  y[1]=cadd(t1,w5); y[5]=csub(t1,w5);
  cplx w6={-t6.y,t6.x};
  y[2]=cadd(t2,w6); y[6]=csub(t2,w6);
  cplx w7={-S2H*(t7.x+t7.y), S2H*(t7.x-t7.y)};
  y[3]=cadd(t3,w7); y[7]=csub(t3,w7);
}

// -------- 16-point DFT in registers; inverse = exact inverse (gain 16) ----------------
__device__ inline void fft16_fwd(cplx z[16]){
  cplx e[8], o[8];
  #pragma unroll
  for (int t=0;t<8;t++){ e[t]=z[2*t]; o[t]=z[2*t+1]; }
  bf8_fwd(e); bf8_fwd(o);
  #pragma unroll
  for (int p=0;p<8;p++){
    cplx vo = cmul(o[p], W16BR[p]);
    z[2*p]   = cadd(e[p], vo);
    z[2*p+1] = csub(e[p], vo);
  }
}
__device__ inline void fft16_inv(cplx z[16]){
  cplx e[8], o[8];
  #pragma unroll
  for (int p=0;p<8;p++){
    cplx a=z[2*p], b=z[2*p+1];
    e[p] = cadd(a,b);
    o[p] = cmulc(csub(a,b), W16BR[p]);
  }
  bf8_inv(e); bf8_inv(o);
  #pragma unroll
  for (int t=0;t<8;t++){ z[2*t]=e[t]; z[2*t+1]=o[t]; }
}

// A[p] = w_128^{j*br3(p)} via chain from TW[j]
__device__ inline void twchainA(const cplx* TW, int j, cplx A[8]){
  cplx W1 = TW[j];
  cplx W2 = cmul(W1,W1);
  cplx W4 = cmul(W2,W2);
  cplx W6 = cmul(W4,W2);
  A[0] = {1.f,0.f}; A[1] = W4; A[2] = W2; A[3] = W6;
  A[4] = W1; A[5] = cmul(W4,W1); A[6] = cmul(W2,W1); A[7] = cmul(W6,W1);
}

// physical f4-slot for (row y, slot m). extra (y>>3) term keeps col-s2 conflict-free
// under column-grouped waves; constant within a wave's 8 consecutive rows for row passes.
__device__ inline int PH(int y, int m){
  return (y<<6) | ((m ^ ((y&7)*9) ^ ((y>>3)&7)) & 63);
}

// ---------------- wave-local FFT passes -------------------------------------------------
// ROW s1 (this thread: row L, residue-group m). ZT: cols>=64 are zero.
template<bool ZT>
__device__ inline void row_s1_f(float4* S4, const cplx* TW, int L, int m){
  cplx xe[8], xo[8];
  #pragma unroll
  for (int t=0; t<(ZT?4:8); t++){
    float4 v = S4[PH(L, m+8*t)];
    xe[t]={v.x,v.y}; xo[t]={v.z,v.w};
  }
  if (ZT){ bf8_fwd_z(xe); bf8_fwd_z(xo); } else { bf8_fwd(xe); bf8_fwd(xo); }
  cplx A[8]; twchainA(TW, 2*m, A);
  #pragma unroll
  for (int p=0;p<8;p++){
    cplx B = cmul(A[p], W128BR[p]);
    cplx ve = cmul(xe[p], A[p]);
    cplx vo = cmul(xo[p], B);
    S4[PH(L, m+8*p)] = {ve.x, ve.y, vo.x, vo.y};
  }
}
__device__ inline void row_s1_i(float4* S4, const cplx* TW, int L, int m){
  cplx xe[8], xo[8];
  #pragma unroll
  for (int p=0;p<8;p++){
    float4 v = S4[PH(L, m+8*p)];
    xe[p]={v.x,v.y}; xo[p]={v.z,v.w};
  }
  cplx A[8]; twchainA(TW, 2*m, A);
  #pragma unroll
  for (int p=0;p<8;p++){
    cplx B = cmul(A[p], W128BR[p]);
    xe[p] = cmulc(xe[p], A[p]);
    xo[p] = cmulc(xo[p], B);
  }
  bf8_inv(xe); bf8_inv(xo);
  #pragma unroll
  for (int t=0;t<4;t++)
    S4[PH(L, m+8*t)] = {xe[t].x, xe[t].y, xo[t].x, xo[t].y};
}
__device__ inline void row_s2_f(float4* S4, int L, int jb){
  cplx z[16];
  #pragma unroll
  for (int k=0;k<8;k++){
    float4 v = S4[PH(L, jb*8+k)];
    z[2*k]={v.x,v.y}; z[2*k+1]={v.z,v.w};
  }
  fft16_fwd(z);
  #pragma unroll
  for (int k=0;k<8;k++)
    S4[PH(L, jb*8+k)] = {z[2*k].x, z[2*k].y, z[2*k+1].x, z[2*k+1].y};
}
__device__ inline void row_s2_i(float4* S4, int L, int jb){
  cplx z[16];
  #pragma unroll
  for (int k=0;k<8;k++){
    float4 v = S4[PH(L, jb*8+k)];
    z[2*k]={v.x,v.y}; z[2*k+1]={v.z,v.w};
  }
  fft16_inv(z);
  #pragma unroll
  for (int k=0;k<8;k++)
    S4[PH(L, jb*8+k)] = {z[2*k].x, z[2*k].y, z[2*k+1].x, z[2*k+1].y};
}
// COL s1 (this thread: residue row yj, slot-col sc)
template<bool ZT>
__device__ inline void col_s1_f(float4* S4, const cplx* TW, int yj, int sc){
  cplx xe[8], xo[8];
  #pragma unroll
  for (int t=0; t<(ZT?4:8); t++){
    float4 v = S4[PH(yj+16*t, sc)];
    xe[t]={v.x,v.y}; xo[t]={v.z,v.w};
  }
  if (ZT){ bf8_fwd_z(xe); bf8_fwd_z(xo); } else { bf8_fwd(xe); bf8_fwd(xo); }
  cplx A[8]; twchainA(TW, yj, A);
  #pragma unroll
  for (int p=0;p<8;p++){
    cplx ve = cmul(xe[p], A[p]);
    cplx vo = cmul(xo[p], A[p]);
    S4[PH(yj+16*p, sc)] = {ve.x, ve.y, vo.x, vo.y};
  }
}
__device__ inline void col_s1_i(float4* S4, const cplx* TW, int yj, int sc){
  cplx xe[8], xo[8];
  #pragma unroll
  for (int p=0;p<8;p++){
    float4 v = S4[PH(yj+16*p, sc)];
    xe[p]={v.x,v.y}; xo[p]={v.z,v.w};
  }
  cplx A[8]; twchainA(TW, yj, A);
  #pragma unroll
  for (int p=0;p<8;p++){
    xe[p] = cmulc(xe[p], A[p]);
    xo[p] = cmulc(xo[p], A[p]);
  }
  bf8_inv(xe); bf8_inv(xo);
  #pragma unroll
  for (int t=0;t<4;t++)
    S4[PH(yj+16*t, sc)] = {xe[t].x, xe[t].y, xo[t].x, xo[t].y};
}

// ---------------- wave-shuffle block reductions ----------------
__device__ inline float wred(float v){
  #pragma unroll
  for (int o=32;o;o>>=1) v += __shfl_xor(v, o, 64);
  return v;
}
__device__ inline float wredmax(float v){
  #pragma unroll
  for (int o=32;o;o>>=1) v = fmaxf(v, __shfl_xor(v, o, 64));
  return v;
}
template<int NW>
__device__ inline void bred3(float& a, float& b, float& c,
                             float* s0, float* s1, float* s2, int tid){
  a = wred(a); b = wred(b); c = wred(c);
  const int w = tid >> 6;
  if ((tid & 63) == 0){ s0[w]=a; s1[w]=b; s2[w]=c; }
  __syncthreads();
  if (tid == 0){
    float A=0.f, B=0.f, C=0.f;
    #pragma unroll
    for (int i=0;i<NW;i++){ A+=s0[i]; B+=s1[i]; C+=s2[i]; }
    s0[0]=A; s1[0]=B; s2[0]=C;
  }
  __syncthreads();
  a = s0[0]; b = s1[0]; c = s2[0];
  __syncthreads();
}
template<int NW>
__device__ inline float bredmax(float v, float* s0, int tid){
  v = wredmax(v);
  const int w = tid >> 6;
  if ((tid & 63) == 0) s0[w] = v;
  __syncthreads();
  if (tid == 0){
    float M = s0[0];
    #pragma unroll
    for (int i=1;i<NW;i++) M = fmaxf(M, s0[i]);
    s0[0] = M;
  }
  __syncthreads();
  const float r = s0[0];
  __syncthreads();
  return r;
}

__device__ inline cplx wval(int r, int c, int which){
  const int dy = (r<64)? r : r-128;
  const int dx = (c<64)? c : c-128;
  float a, b;
  if (which==0){ a = 1.f-(float)dy; b = 1.f-(float)dx; }
  else         { a = 1.f+(float)dy; b = 1.f+(float)dx; }
  const float den = a*a + b*b;
  if (r==64 || c==64 || den<=0.f) return {0.f,0.f};
  const float inv = 1.f/den;
  return {a*inv, -b*inv};
}

// ---------------- pre: blk 0,1 = kernel-FFT prep; rest = stats ------------------------
__global__ __launch_bounds__(TPB,4) void pre_kernel(const float* __restrict__ heat,
                                                    const float* __restrict__ fields,
                                                    const int* __restrict__ ishape,
                                                    float* __restrict__ mean_hm,
                                                    float* __restrict__ std_hm,
                                                    float* __restrict__ sf,
                                                    float* __restrict__ W1,
                                                    float* __restrict__ W2,
                                                    float* __restrict__ out){
  __shared__ float4 S4[8192];
  __shared__ cplx TW[128];
  __shared__ float sA[16], sB[16], sC[16];
  const int tid = threadIdx.x;
  const int wv = tid >> 6, lane = tid & 63;
  const int blk = blockIdx.x;
  if (blk < 2){
    const int which = blk;
    if (tid < 128){
      float s, c;
      sincosf(-6.283185307179586f * (float)tid / 128.0f, &s, &c);
      TW[tid] = {c, s};
    }
    for (int s = tid; s < 8192; s += TPB){
      const int y = s>>6, m = s&63;
      const cplx v0 = wval(y, 2*m, which);
      const cplx v1 = wval(y, 2*m+1, which);
      S4[PH(y, m)] = {v0.x, v0.y, v1.x, v1.y};
    }
    __syncthreads();
    { // rows: wave w owns rows 8w..8w+7, wave-local s1 -> s2
      const int L = 8*wv + (lane>>3), m = lane&7;
      row_s1_f<false>(S4, TW, L, m);
      wsync();
      row_s2_f(S4, L, m);
    }
    __syncthreads();
    { // cols: wave w owns slot-cols 4w..4w+3
      const int yj = lane & 15, sc = 4*wv + (lane>>4);
      col_s1_f<false>(S4, TW, yj, sc);
      wsync();
      // col s2 forward + store spectrum (wave-local cols)
      cplx* Sc = (cplx*)S4;
      const int c = 8*wv + (lane&7), r = lane>>3;
      cplx z[16];
      #pragma unroll
      for (int i=0;i<16;i++)
        z[i] = Sc[2*PH(16*r+i, c>>1) + (c&1)];
      fft16_fwd(z);
      cplx* Wo = (cplx*)((which==0)?W1:W2);
      const float scl = 1.0f / 16384.0f;
      #pragma unroll
      for (int i=0;i<16;i++) Wo[(16*r+i)*128 + c] = {z[i].x*scl, z[i].y*scl};
    }
  } else if (blk < 274){
    const int n = blk - 2;
    const float4* p4 = (const float4*)(heat + (size_t)n * NPIX);
    const float4 x = p4[tid];
    float s = x.x+x.y+x.z+x.w;
    float s2 = x.x*x.x + x.y*x.y + x.z*x.z + x.w*x.w;
    float d = 0.0f;
    bred3<16>(s, s2, d, sA, sB, sC, tid);
    if (tid == 0){
      const float mean = s / 4096.0f;
      const float var = (s2 - s*mean) / 4095.0f;
      mean_hm[n] = mean;
      std_hm[n] = sqrtf(fmaxf(var, 0.0f));
    }
  } else {
    const int m = blk - 274;
    const float4* F4 = (const float4*)(fields + (size_t)m * 3 * NPIX);
    const float4 f0 = F4[tid], f1 = F4[1024+tid], f2 = F4[2048+tid];
    const float f0a[4] = {f0.x,f0.y,f0.z,f0.w};
    const float f1a[4] = {f1.x,f1.y,f1.z,f1.w};
    const float f2a[4] = {f2.x,f2.y,f2.z,f2.w};
    float fn[4];
    float s1 = 0.0f, s2 = 0.0f;
    float a0 = 0.0f, a1 = 0.0f, a2 = 0.0f;
    #pragma unroll
    for (int j = 0; j < 4; j++){
      s1 += f0a[j]+f1a[j]+f2a[j];
      s2 += f0a[j]*f0a[j]+f1a[j]*f1a[j]+f2a[j]*f2a[j];
      const float nn = sqrtf(f0a[j]*f0a[j] + f1a[j]*f1a[j] + f2a[j]*f2a[j]);
      fn[j] = nn;
      a0 += nn*f0a[j]; a1 += nn*f1a[j]; a2 += nn*f2a[j];
    }
    {
      float t1 = s1, t2 = s2, t3 = 0.0f;
      bred3<16>(t1, t2, t3, sA, sB, sC, tid);
      if (tid == 0){
        const float var = (t2 - t1*t1/12288.0f) / 12287.0f;
        const float sd = sqrtf(fmaxf(var, 0.0f));
        sf[m] = sd / (sd + 1e-6f);
      }
    }
    bred3<16>(a0, a1, a2, sA, sB, sC, tid);
    float mx = fmaxf(fmaxf(fn[0],fn[1]), fmaxf(fn[2],fn[3]));
    mx = bredmax<16>(mx, sA, tid);
    float Sm = 0.0f, Sx = 0.0f, Sy = 0.0f;
    #pragma unroll
    for (int j = 0; j < 4; j++){
      const int px = tid*4 + j;
      const float e = expf(kBeta * (fn[j] - mx));
      Sm += e; Sx += e * (float)(px>>6); Sy += e * (float)(px&63);
    }
    bred3<16>(Sm, Sx, Sy, sA, sB, sC, tid);
    if (tid == 0){
      float nrm = sqrtf(a0*a0 + a1*a1 + a2*a2);
      nrm = fmaxf(nrm, 1e-12f);
      out[O_CV + m*3 + 0] = a0/nrm;
      out[O_CV + m*3 + 1] = a1/nrm;
      out[O_CV + m*3 + 2] = a2/nrm;
      const float sxs = (float)ishape[1] / 64.0f;
      const float sys = (float)ishape[0] / 64.0f;
      out[O_CP + m*2 + 0] = Sx/Sm * sxs;
      out[O_CP + m*2 + 1] = Sy/Sm * sys;
    }
  }
}

// ---------------- conv: blocks 0..255 conv2, 256..511 conv1 ----------------
__global__ __launch_bounds__(TPB,4) void conv_kernel(const float* __restrict__ heat,
                                                     const float* __restrict__ mean_hm,
                                                     const float* __restrict__ fields,
                                                     const float* __restrict__ sf,
                                                     const float* __restrict__ W1g,
                                                     const float* __restrict__ W2g,
                                                     float* __restrict__ out_fn,
                                                     float* __restrict__ fds){
  __shared__ float4 S4[8192];
  __shared__ cplx TW[128];
  const int tid = threadIdx.x;
  const int wv = tid >> 6, lane = tid & 63;
  const int n = blockIdx.x;
  const bool is2 = (n < 256);
  const int m_img = is2 ? n : (n - 256);
  if (tid < 128){
    float s, c;
    sincosf(-6.283185307179586f * (float)tid / 128.0f, &s, &c);
    TW[tid] = {c, s};
  }
  const float* f = fields + (size_t)m_img * 3 * NPIX;
  // stage-in: thread u covers 4 consecutive pixels -> 2 f4 slots
  {
    const int y = tid >> 4, x4 = (tid & 15) << 2;
    const int i = (y << 6) + x4;
    const int m = (tid & 15) << 1;
    if (!is2){
      const int bv = m_img >> 4, l = m_img & 15;
      const int j1 = bv*NJ + c_P1[l], j0 = bv*NJ + c_P0[l];
      const float dm = mean_hm[j1] - mean_hm[j0];
      const float4 a = *(const float4*)(heat + (size_t)j1*NPIX + i);
      const float4 b = *(const float4*)(heat + (size_t)j0*NPIX + i);
      S4[PH(y, m  )] = {a.x-b.x-dm, 0.f, a.y-b.y-dm, 0.f};
      S4[PH(y, m+1)] = {a.z-b.z-dm, 0.f, a.w-b.w-dm, 0.f};
    } else {
      const float4 A = *(const float4*)(f + NPIX + i);   // ch1 -> re
      const float4 B = *(const float4*)(f + i);          // ch0 -> im
      S4[PH(y, m  )] = {A.x, B.x, A.y, B.y};
      S4[PH(y, m+1)] = {A.z, B.z, A.w, B.w};
    }
  }
  __syncthreads();                       // B1
  // ROWS FWD: waves 0..7 own rows 8w..8w+7 (wave-local)
  if (wv < 8){
    const int L = 8*wv + (lane>>3), m = lane&7;
    row_s1_f<true>(S4, TW, L, m);
    wsync();
    row_s2_f(S4, L, m);
  }
  __syncthreads();                       // B2 (transpose)
  // COLS: all waves; wave w owns slot-cols 4w..4w+3 (wave-local full chain)
  {
    const cplx* Wg = (const cplx*)(is2 ? W2g : W1g);
    const int c = 8*wv + (lane&7), r = lane>>3;
    cplx wvv[16];
    #pragma unroll
    for (int i=0;i<16;i++) wvv[i] = Wg[(16*r+i)*128 + c];   // prefetch, consumed after s1
    const int yj = lane & 15, sc = 4*wv + (lane>>4);
    col_s1_f<true>(S4, TW, yj, sc);
    wsync();
    {
      cplx* Sc = (cplx*)S4;
      cplx z[16];
      int ad[16];
      #pragma unroll
      for (int i=0;i<16;i++){
        ad[i] = 2*PH(16*r+i, c>>1) + (c&1);
        z[i] = Sc[ad[i]];
      }
      fft16_fwd(z);
      #pragma unroll
      for (int i=0;i<16;i++) z[i] = cmul(z[i], wvv[i]);
      fft16_inv(z);
      #pragma unroll
      for (int i=0;i<16;i++) Sc[ad[i]] = z[i];
    }
    wsync();
    col_s1_i(S4, TW, yj, sc);
  }
  __syncthreads();                       // B3
  // ROWS INV: waves 0..7
  if (wv < 8){
    const int L = 8*wv + (lane>>3), m = lane&7;
    row_s2_i(S4, L, m);
    wsync();
    row_s1_i(S4, TW, L, m);
  }
  __syncthreads();                       // B4
  // epilogue: thread covers 4 consecutive pixels
  {
    const int y = tid >> 4, x4 = (tid & 15) << 2;
    const int i = (y << 6) + x4;
    const int m = (tid & 15) << 1;
    const float4 va = S4[PH(y, m)];
    const float4 vb = S4[PH(y, m+1)];
    if (!is2){
      float* o = out_fn + (size_t)m_img * 3 * NPIX;
      const float4 f0 = *(const float4*)(f + i);
      const float4 f1 = *(const float4*)(f + NPIX + i);
      const float4 f2 = *(const float4*)(f + 2*NPIX + i);
      const float c0[4] = {-va.y, -va.w, -vb.y, -vb.w};
      const float c1[4] = { va.x,  va.z,  vb.x,  vb.z};
      const float f0a[4] = {f0.x,f0.y,f0.z,f0.w};
      const float f1a[4] = {f1.x,f1.y,f1.z,f1.w};
      const float f2a[4] = {f2.x,f2.y,f2.z,f2.w};
      float o0[4], o1[4], o2[4];
      #pragma unroll
      for (int j=0;j<4;j++){
        const float cf = fmaxf(0.f, c0[j]*f0a[j] + c1[j]*f1a[j]);
        o0[j] = f0a[j]*cf; o1[j] = f1a[j]*cf; o2[j] = f2a[j]*cf;
      }
      *(float4*)(o + i)          = {o0[0],o0[1],o0[2],o0[3]};
      *(float4*)(o + NPIX + i)   = {o1[0],o1[1],o1[2],o1[3]};
      *(float4*)(o + 2*NPIX + i) = {o2[0],o2[1],o2[2],o2[3]};
    } else {
      const float sc2 = sf[m_img];
      float* o = fds + (size_t)m_img * NPIX;
      *(float4*)(o + i) = {va.x*sc2, va.z*sc2, vb.x*sc2, vb.z*sc2};
    }
  }
}

// ---------------- hms_new + normalize + soft-argmax + kps combine ----------------
__global__ __launch_bounds__(HTPB) void hms_kernel(const float* __restrict__ heat,
                                                   const float* __restrict__ mean_hm,
                                                   const float* __restrict__ std_hm,
                                                   const float* __restrict__ fds,
                                                   const float* __restrict__ confs,
                                                   const int* __restrict__ ishape,
                                                   const float* __restrict__ pth1p,
                                                   const float* __restrict__ pth2p,
                                                   float* __restrict__ out){
  __shared__ float sA[4], sB[4], sC[4];
  const int tid = threadIdx.x;
  const int idx = blockIdx.x;           // bv*17 + j
  const int bv = idx / NJ, j = idx % NJ;
  const float4* hp4 = (const float4*)(heat + (size_t)idx * NPIX);
  const float mh = mean_hm[idx];
  const int pl = c_proxL[j], dl = c_distL[j];
  const float4* fp4 = (pl >= 0) ? (const float4*)(fds + (size_t)(bv*NL + pl) * NPIX) : nullptr;
  const float4* fd4 = (dl >= 0) ? (const float4*)(fds + (size_t)(bv*NL + dl) * NPIX) : nullptr;
  float ho[16], hn[16];
  float s = 0.0f, s2 = 0.0f, dummy = 0.0f;
  #pragma unroll
  for (int i = 0; i < 4; i++){
    const int u = tid + i*HTPB;
    const float4 h4 = hp4[u];
    const float hv[4] = {h4.x-mh, h4.y-mh, h4.z-mh, h4.w-mh};
    float pv[4] = {1.f,1.f,1.f,1.f};
    if (pl >= 0){
      const float4 p4 = fp4[u];
      pv[0] = fmaxf(0.f,-p4.x); pv[1] = fmaxf(0.f,-p4.y);
      pv[2] = fmaxf(0.f,-p4.z); pv[3] = fmaxf(0.f,-p4.w);
    }
    float dv[4] = {1.f,1.f,1.f,1.f};
    if (dl >= 0){
      const float4 d4 = fd4[u];
      dv[0] = fmaxf(0.f,d4.x); dv[1] = fmaxf(0.f,d4.y);
      dv[2] = fmaxf(0.f,d4.z); dv[3] = fmaxf(0.f,d4.w);
    }
    #pragma unroll
    for (int k=0;k<4;k++){
      ho[4*i+k] = hv[k];
      const float m = hv[k]*pv[k]*dv[k];
      hn[4*i+k] = m;
      s += m; s2 += m*m;
    }
  }
  bred3<4>(s, s2, dummy, sA, sB, sC, tid);
  const float var = (s2 - s*s/4096.0f) / 4095.0f;
  const float sdn = sqrtf(fmaxf(var, 0.0f));
  const float scale = std_hm[idx] / (sdn + 1e-6f);
  float4* ohm4 = (float4*)(out + O_HM + (size_t)idx * NPIX);
  #pragma unroll
  for (int i = 0; i < 4; i++){
    #pragma unroll
    for (int k=0;k<4;k++) hn[4*i+k] *= scale;
    ohm4[tid + i*HTPB] = {hn[4*i], hn[4*i+1], hn[4*i+2], hn[4*i+3]};
  }
  float mo = -1e30f, mn = -1e30f;
  #pragma unroll
  for (int i = 0; i < 16; i++){ mo = fmaxf(mo, ho[i]); mn = fmaxf(mn, hn[i]); }
  mo = bredmax<4>(mo, sA, tid);
  mn = bredmax<4>(mn, sA, tid);
  float So = 0.0f, Sxo = 0.0f, Syo = 0.0f;
  float Sn = 0.0f, Sxn = 0.0f, Syn = 0.0f;
  #pragma unroll
  for (int i = 0; i < 16; i++){
    const int px = (tid + (i>>2)*HTPB)*4 + (i&3);
    const float y = (float)(px >> 6), x = (float)(px & 63);
    const float eo = expf(kBeta * (ho[i] - mo));
    So += eo; Sxo += eo*y; Syo += eo*x;
    const float en = expf(kBeta * (hn[i] - mn));
    Sn += en; Sxn += en*y; Syn += en*x;
  }
  bred3<4>(So, Sxo, Syo, sA, sB, sC, tid);
  bred3<4>(Sn, Sxn, Syn, sA, sB, sC, tid);
  if (tid == 0){
    const float sxs = (float)ishape[1] / 64.0f;
    const float sys = (float)ishape[0] / 64.0f;
    const float kxo = Sxo/So * sxs, kyo = Syo/So * sys;
    float kxn = Sxn/Sn * sxs, kyn = Syn/Sn * sys;
    if (kxn != kxn) kxn = kxo;
    if (kyn != kyn) kyn = kyo;
    const float ddx = kxn - kxo, ddy = kyn - kyo;
    const float disp = sqrtf(ddx*ddx + ddy*ddy);
    const float conf = confs[bv*(NL+NJ) + NL + j];
    const bool sel = (conf > pth1p[0]) && (disp < pth2p[0]);
    out[O_KPS + idx*2 + 0] = sel ? kxn : kxo;
    out[O_KPS + idx*2 + 1] = sel ? kyn : kyo;
  }
}

extern "C" void kernel_launch(void* const* d_in, const int* in_sizes, int n_in,
                              void* d_out, int out_size, void* d_ws, size_t ws_size,
                              hipStream_t stream) {
  const float* heat   = (const float*)d_in[0];
  const float* fields = (const float*)d_in[1];
  const int*   ishape = (const int*)d_in[5];
  const float* confs  = (const float*)d_in[6];
  const float* pth1   = (const float*)d_in[9];
  const float* pth2   = (const float*)d_in[10];
  float* out = (float*)d_out;
  float* ws = (float*)d_ws;
  float* fds     = ws + W_FDS;
  float* mean_hm = ws + W_MEAN;
  float* std_hm  = ws + W_STD;
  float* sf      = ws + W_SF;
  float* W1      = ws + W_W1;
  float* W2      = ws + W_W2;

  hipLaunchKernelGGL(pre_kernel, dim3(530), dim3(TPB), 0, stream,
                     heat, fields, ishape, mean_hm, std_hm, sf, W1, W2, out);
  hipLaunchKernelGGL(conv_kernel, dim3(512), dim3(TPB), 0, stream,
                     heat, mean_hm, fields, sf, W1, W2, out + O_FN, fds);
  hipLaunchKernelGGL(hms_kernel, dim3(272), dim3(HTPB), 0, stream,
                     heat, mean_hm, std_hm, fds, confs, ishape, pth1, pth2, out);
}